// Round 1
// baseline (1157.198 us; speedup 1.0000x reference)
//
#include <hip/hip_runtime.h>

#define B_  4
#define S_  1024
#define D_  512
#define H_  8
#define DH_ 64
#define SCALE 0.044194173824159216f  // 1/sqrt(512)

// ---------------------------------------------------------------------------
// Shared-memory tiled fp32 GEMM core: C[64x64 tile] = A[M,K] @ W[K,N] (+bias)
// 256 threads, each computes a 4x4 micro-tile. BK=16.
// ---------------------------------------------------------------------------
struct SMem {
    float As[16][65];
    float Bs[16][65];
};

__device__ __forceinline__ void gemm_core(
    SMem& sm,
    const float* __restrict__ A, int lda,
    const float* __restrict__ W, int ldw,
    const float* __restrict__ bias,
    float* __restrict__ C, int ldc,
    int K, int i0, int j0)
{
    const int tid = threadIdx.x;
    const int tx = tid & 15, ty = tid >> 4;
    const int arow = tid >> 2, akk = (tid & 3) << 2;   // A tile: 64 rows x 16 k
    const int brow = tid >> 4, bnn = (tid & 15) << 2;  // B tile: 16 rows x 64 n
    float acc[4][4] = {};

    for (int k0 = 0; k0 < K; k0 += 16) {
        float4 va = *reinterpret_cast<const float4*>(&A[(size_t)(i0 + arow) * lda + (k0 + akk)]);
        float4 vb = *reinterpret_cast<const float4*>(&W[(size_t)(k0 + brow) * ldw + (j0 + bnn)]);
        sm.As[akk + 0][arow] = va.x;
        sm.As[akk + 1][arow] = va.y;
        sm.As[akk + 2][arow] = va.z;
        sm.As[akk + 3][arow] = va.w;
        sm.Bs[brow][bnn + 0] = vb.x;
        sm.Bs[brow][bnn + 1] = vb.y;
        sm.Bs[brow][bnn + 2] = vb.z;
        sm.Bs[brow][bnn + 3] = vb.w;
        __syncthreads();
#pragma unroll
        for (int kk = 0; kk < 16; ++kk) {
            float a[4], b[4];
#pragma unroll
            for (int e = 0; e < 4; ++e) { a[e] = sm.As[kk][ty * 4 + e]; b[e] = sm.Bs[kk][tx * 4 + e]; }
#pragma unroll
            for (int i = 0; i < 4; ++i)
#pragma unroll
                for (int j = 0; j < 4; ++j) acc[i][j] = fmaf(a[i], b[j], acc[i][j]);
        }
        __syncthreads();
    }

#pragma unroll
    for (int i = 0; i < 4; ++i) {
        const int r = i0 + ty * 4 + i;
#pragma unroll
        for (int j = 0; j < 4; ++j) {
            const int c = j0 + tx * 4 + j;
            float o = acc[i][j];
            if (bias) o += bias[c];
            C[(size_t)r * ldc + c] = o;
        }
    }
}

__global__ __launch_bounds__(256) void gemm_bias_k(
    const float* __restrict__ A, int lda,
    const float* __restrict__ W, int ldw,
    const float* __restrict__ bias,
    float* __restrict__ C, int ldc, int K)
{
    __shared__ SMem sm;
    gemm_core(sm, A, lda, W, ldw, bias, C, ldc, K, blockIdx.x * 64, blockIdx.y * 64);
}

// context[b,s,h,d] = sum_t attn[b,h,s,t] * v[b,t,h,d]   (per (b,h) GEMM)
__global__ __launch_bounds__(256) void context_gemm_k(
    const float* __restrict__ attn,
    const float* __restrict__ v,
    float* __restrict__ ctx)
{
    __shared__ SMem sm;
    const int bh = blockIdx.z;
    const int b = bh >> 3, h = bh & 7;
    gemm_core(sm,
              attn + (size_t)bh * S_ * S_, S_,
              v + (size_t)b * S_ * D_ + h * DH_, D_,
              nullptr,
              ctx + (size_t)b * S_ * D_ + h * DH_, D_,
              S_, blockIdx.x * 64, 0);
}

// ---------------------------------------------------------------------------
// Transpose [B,S,H,DH] -> [B,H,DH,S] so score-kernel reads are lane-coalesced
// ---------------------------------------------------------------------------
__global__ __launch_bounds__(256) void transpose_heads_k(
    const float* __restrict__ src, float* __restrict__ dst)
{
    const int d = blockIdx.x;            // 0..63
    const int bh = blockIdx.y;           // 0..31
    const int b = bh >> 3, h = bh & 7;
    float* drow = dst + ((size_t)bh * DH_ + d) * S_;
    const float* s0 = src + (size_t)b * S_ * D_ + h * DH_ + d;
    for (int t = threadIdx.x; t < S_; t += 256)
        drow[t] = s0[(size_t)t * D_];
}

// ---------------------------------------------------------------------------
// Fused content+pos score (with relative shift gather) + softmax.
// One block (256 threads) per attention row (b,h,i). Each thread owns 4 cols.
//
// shifted[i,j] = Rpos[i,   S-1+j-i]  for j <= i
//              = 0                   for j == i+1
//              = Rpos[i+1, j-i-2]    for j >= i+2
// where Rpos[s,u] = (q[s]+v_bias) . p[u]
// ---------------------------------------------------------------------------
__global__ __launch_bounds__(256) void score_softmax_k(
    const float* __restrict__ q,      // [B,S,D] ([B,S,H,DH])
    const float* __restrict__ kt,     // [B,H,DH,S]
    const float* __restrict__ pt,     // [B,H,DH,S]
    const float* __restrict__ u_bias, // [H,DH]
    const float* __restrict__ v_bias, // [H,DH]
    float* __restrict__ attn)         // [B,H,S,S]
{
    const int r  = blockIdx.x;        // (b*H + h)*S + i
    const int i  = r & (S_ - 1);
    const int bh = r >> 10;
    const int b  = bh >> 3, h = bh & 7;
    const int tid = threadIdx.x;

    __shared__ float qu[DH_], qv0[DH_], qv1[DH_];
    if (tid < DH_) {
        const int d = tid;
        const float qq  = q[((size_t)(b * S_ + i)) * D_ + h * DH_ + d];
        const int ip1   = (i + 1 < S_) ? (i + 1) : i;
        const float qq1 = q[((size_t)(b * S_ + ip1)) * D_ + h * DH_ + d];
        const float vb  = v_bias[h * DH_ + d];
        qu[d]  = qq + u_bias[h * DH_ + d];
        qv0[d] = qq + vb;
        qv1[d] = qq1 + vb;
    }
    __syncthreads();

    const float* ktb = kt + (size_t)bh * DH_ * S_;
    const float* ptb = pt + (size_t)bh * DH_ * S_;

    float sc[4];
#pragma unroll
    for (int m = 0; m < 4; ++m) {
        const int j = tid + m * 256;
        float c = 0.f;
#pragma unroll 8
        for (int d = 0; d < DH_; ++d) c = fmaf(qu[d], ktb[d * S_ + j], c);
        float p = 0.f;
        if (j != i + 1) {
            const float* qv;
            int u;
            if (j <= i) { qv = qv0; u = S_ - 1 + j - i; }
            else        { qv = qv1; u = j - i - 2; }
#pragma unroll 8
            for (int d = 0; d < DH_; ++d) p = fmaf(qv[d], ptb[d * S_ + u], p);
        }
        sc[m] = (c + p) * SCALE;
    }

    // block-wide softmax over the 1024 scores
    __shared__ float redm[4], reds[4];
    const int wave = tid >> 6, lane = tid & 63;

    float mx = fmaxf(fmaxf(sc[0], sc[1]), fmaxf(sc[2], sc[3]));
#pragma unroll
    for (int off = 32; off > 0; off >>= 1) mx = fmaxf(mx, __shfl_xor(mx, off));
    if (lane == 0) redm[wave] = mx;
    __syncthreads();
    mx = fmaxf(fmaxf(redm[0], redm[1]), fmaxf(redm[2], redm[3]));

    float e[4];
    float sum = 0.f;
#pragma unroll
    for (int m = 0; m < 4; ++m) { e[m] = __expf(sc[m] - mx); sum += e[m]; }
#pragma unroll
    for (int off = 32; off > 0; off >>= 1) sum += __shfl_xor(sum, off);
    if (lane == 0) reds[wave] = sum;
    __syncthreads();
    sum = reds[0] + reds[1] + reds[2] + reds[3];

    const float inv = 1.f / sum;
    float* arow = attn + (size_t)r * S_;
#pragma unroll
    for (int m = 0; m < 4; ++m) arow[tid + m * 256] = e[m] * inv;
}

// ---------------------------------------------------------------------------
extern "C" void kernel_launch(void* const* d_in, const int* in_sizes, int n_in,
                              void* d_out, int out_size, void* d_ws, size_t ws_size,
                              hipStream_t stream)
{
    const float* query = (const float*)d_in[0];
    const float* key_  = (const float*)d_in[1];
    const float* value = (const float*)d_in[2];
    const float* pose  = (const float*)d_in[3];
    const float* Wq = (const float*)d_in[4];
    const float* bq = (const float*)d_in[5];
    const float* Wk = (const float*)d_in[6];
    const float* bk = (const float*)d_in[7];
    const float* Wv = (const float*)d_in[8];
    const float* bv = (const float*)d_in[9];
    const float* Wp = (const float*)d_in[10];
    const float* Wo = (const float*)d_in[11];
    const float* bo = (const float*)d_in[12];
    const float* u_bias = (const float*)d_in[13];
    const float* v_bias = (const float*)d_in[14];

    const size_t NTOK = (size_t)B_ * S_ * D_;  // 2,097,152
    float* out  = (float*)d_out;               // [B,S,D]
    float* attn = (float*)d_out + NTOK;        // [B,H,S,S]

    float* ws = (float*)d_ws;
    float* q  = ws;             // [B,S,D]
    float* k  = ws + NTOK;      // [B,S,D]  (reused as ctx later)
    float* v  = ws + 2 * NTOK;  // [B,S,D]
    float* p  = ws + 3 * NTOK;  // [B,S,D]
    float* kt = ws + 4 * NTOK;  // [B,H,DH,S]
    float* pt = out;            // [B,H,DH,S] staged in d_out's out-region,
                                // overwritten by the final projection GEMM
    float* ctx = k;             // k's raw buffer is dead after the transpose

    const dim3 blk(256);
    const dim3 gproj(64, 8);    // M=4096/64, N=512/64

    gemm_bias_k<<<gproj, blk, 0, stream>>>(query, D_, Wq, D_, bq, q, D_, D_);
    gemm_bias_k<<<gproj, blk, 0, stream>>>(key_,  D_, Wk, D_, bk, k, D_, D_);
    gemm_bias_k<<<gproj, blk, 0, stream>>>(value, D_, Wv, D_, bv, v, D_, D_);
    gemm_bias_k<<<gproj, blk, 0, stream>>>(pose,  D_, Wp, D_, nullptr, p, D_, D_);

    transpose_heads_k<<<dim3(DH_, B_ * H_), blk, 0, stream>>>(k, kt);
    transpose_heads_k<<<dim3(DH_, B_ * H_), blk, 0, stream>>>(p, pt);

    score_softmax_k<<<dim3(B_ * H_ * S_), blk, 0, stream>>>(q, kt, pt, u_bias, v_bias, attn);

    context_gemm_k<<<dim3(S_ / 64, 1, B_ * H_), blk, 0, stream>>>(attn, v, ctx);

    gemm_bias_k<<<gproj, blk, 0, stream>>>(ctx, D_, Wo, D_, bo, out, D_, D_);
}

// Round 3
// 396.518 us; speedup vs baseline: 2.9184x; 2.9184x over previous
//
#include <hip/hip_runtime.h>

#define B_  4
#define S_  1024
#define D_  512
#define H_  8
#define DH_ 64
#define SCALE 0.044194173824159216f  // 1/sqrt(512)

typedef short bf16x8 __attribute__((ext_vector_type(8)));
typedef float f32x4  __attribute__((ext_vector_type(4)));

__device__ __forceinline__ unsigned short f2bf(float x) {
    union { float f; unsigned int u; } v; v.f = x;
    unsigned int r = v.u + 0x7fffu + ((v.u >> 16) & 1u);
    return (unsigned short)(r >> 16);
}
__device__ __forceinline__ float bf2f(unsigned short h) {
    union { unsigned int u; float f; } v; v.u = ((unsigned int)h) << 16;
    return v.f;
}

// ===========================================================================
// fp32 tiled GEMM (round-1, kept for the exact v->context->out path)
// ===========================================================================
struct SMem {
    float As[16][65];
    float Bs[16][65];
};

__device__ __forceinline__ void gemm_core(
    SMem& sm,
    const float* __restrict__ A, int lda,
    const float* __restrict__ W, int ldw,
    const float* __restrict__ bias,
    float* __restrict__ C, int ldc,
    int K, int i0, int j0)
{
    const int tid = threadIdx.x;
    const int tx = tid & 15, ty = tid >> 4;
    const int arow = tid >> 2, akk = (tid & 3) << 2;
    const int brow = tid >> 4, bnn = (tid & 15) << 2;
    float acc[4][4] = {};

    for (int k0 = 0; k0 < K; k0 += 16) {
        float4 va = *reinterpret_cast<const float4*>(&A[(size_t)(i0 + arow) * lda + (k0 + akk)]);
        float4 vb = *reinterpret_cast<const float4*>(&W[(size_t)(k0 + brow) * ldw + (j0 + bnn)]);
        sm.As[akk + 0][arow] = va.x;
        sm.As[akk + 1][arow] = va.y;
        sm.As[akk + 2][arow] = va.z;
        sm.As[akk + 3][arow] = va.w;
        sm.Bs[brow][bnn + 0] = vb.x;
        sm.Bs[brow][bnn + 1] = vb.y;
        sm.Bs[brow][bnn + 2] = vb.z;
        sm.Bs[brow][bnn + 3] = vb.w;
        __syncthreads();
#pragma unroll
        for (int kk = 0; kk < 16; ++kk) {
            float a[4], b[4];
#pragma unroll
            for (int e = 0; e < 4; ++e) { a[e] = sm.As[kk][ty * 4 + e]; b[e] = sm.Bs[kk][tx * 4 + e]; }
#pragma unroll
            for (int i = 0; i < 4; ++i)
#pragma unroll
                for (int j = 0; j < 4; ++j) acc[i][j] = fmaf(a[i], b[j], acc[i][j]);
        }
        __syncthreads();
    }

#pragma unroll
    for (int i = 0; i < 4; ++i) {
        const int r = i0 + ty * 4 + i;
#pragma unroll
        for (int j = 0; j < 4; ++j) {
            const int c = j0 + tx * 4 + j;
            float o = acc[i][j];
            if (bias) o += bias[c];
            C[(size_t)r * ldc + c] = o;
        }
    }
}

__global__ __launch_bounds__(256) void gemm_bias_k(
    const float* __restrict__ A, int lda,
    const float* __restrict__ W, int ldw,
    const float* __restrict__ bias,
    float* __restrict__ C, int ldc, int K)
{
    __shared__ SMem sm;
    gemm_core(sm, A, lda, W, ldw, bias, C, ldc, K, blockIdx.x * 64, blockIdx.y * 64);
}

__global__ __launch_bounds__(256) void context_gemm_k(
    const float* __restrict__ attn,
    const float* __restrict__ v,
    float* __restrict__ ctx)
{
    __shared__ SMem sm;
    const int bh = blockIdx.z;
    const int b = bh >> 3, h = bh & 7;
    gemm_core(sm,
              attn + (size_t)bh * S_ * S_, S_,
              v + (size_t)b * S_ * D_ + h * DH_, D_,
              nullptr,
              ctx + (size_t)b * S_ * D_ + h * DH_, D_,
              S_, blockIdx.x * 64, 0);
}

// ===========================================================================
// Weight transpose + bf16 convert: T[o,i] = bf16(W[i,o]) for Wq, Wk, Wp
// ===========================================================================
__global__ __launch_bounds__(256) void convert_wt_k(
    const float* __restrict__ W0, const float* __restrict__ W1, const float* __restrict__ W2,
    unsigned short* __restrict__ T0, unsigned short* __restrict__ T1, unsigned short* __restrict__ T2)
{
    const float* W = (blockIdx.y == 0) ? W0 : (blockIdx.y == 1) ? W1 : W2;
    unsigned short* T = (blockIdx.y == 0) ? T0 : (blockIdx.y == 1) ? T1 : T2;
    const int e = blockIdx.x * 256 + threadIdx.x;   // 512*512 = 262144 total
    const int o = e >> 9, i = e & 511;
    T[(size_t)o * 512 + i] = f2bf(W[(size_t)i * 512 + o]);
}

// ===========================================================================
// bf16 MFMA projection GEMM: C = A @ WT^T (+bias terms), scatter to [B,H,S,DH]
// MODE 0: q -> qu = bf16(acc+bq+u_bias), qv = bf16(acc+bq+v_bias)
// MODE 1: k -> bf16(acc+bk) ; MODE 2: p -> bf16(acc)
// 64x64 tile, BK=64, 4 waves (each a 32x32 quadrant).
// ===========================================================================
template<int MODE>
__global__ __launch_bounds__(256) void proj_mfma(
    const float* __restrict__ A,            // [4096,512] fp32
    const unsigned short* __restrict__ BT,  // [512,512] bf16 (W^T)
    const float* __restrict__ bias,         // [512]
    const float* __restrict__ ub,
    const float* __restrict__ vb,
    unsigned short* __restrict__ out0,      // [B,H,S,DH] bf16
    unsigned short* __restrict__ out1)
{
    __shared__ unsigned short Ab[64][72];
    __shared__ unsigned short Bb[64][72];
    const int tid = threadIdx.x;
    const int i0 = blockIdx.x * 64, j0 = blockIdx.y * 64;
    const int w = tid >> 6, lane = tid & 63, l15 = lane & 15, lhi = lane >> 4;
    const int mr0 = (w >> 1) * 32, nc0 = (w & 1) * 32;
    f32x4 acc[2][2] = {};

    for (int k0 = 0; k0 < 512; k0 += 64) {
        __syncthreads();
#pragma unroll
        for (int it = 0; it < 4; ++it) {            // A: 1024 ushort4 slots (8B each)
            const int s = tid + it * 256;
            const int row = s >> 4, f4 = (s & 15) * 4;
            float4 va = *(const float4*)&A[(size_t)(i0 + row) * 512 + k0 + f4];
            ushort4 hh;
            hh.x = f2bf(va.x); hh.y = f2bf(va.y); hh.z = f2bf(va.z); hh.w = f2bf(va.w);
            *(ushort4*)&Ab[row][f4] = hh;
        }
#pragma unroll
        for (int it = 0; it < 2; ++it) {            // B: 512 slots of 8 shorts (16B each)
            const int s = tid + it * 256;
            const int row = s >> 3, g = (s & 7) * 8;
            *(bf16x8*)&Bb[row][g] = *(const bf16x8*)&BT[(size_t)(j0 + row) * 512 + k0 + g];
        }
        __syncthreads();
#pragma unroll
        for (int kk = 0; kk < 2; ++kk) {
            bf16x8 a0 = *(const bf16x8*)&Ab[mr0 + l15][kk * 32 + lhi * 8];
            bf16x8 a1 = *(const bf16x8*)&Ab[mr0 + 16 + l15][kk * 32 + lhi * 8];
            bf16x8 b0 = *(const bf16x8*)&Bb[nc0 + l15][kk * 32 + lhi * 8];
            bf16x8 b1 = *(const bf16x8*)&Bb[nc0 + 16 + l15][kk * 32 + lhi * 8];
            acc[0][0] = __builtin_amdgcn_mfma_f32_16x16x32_bf16(a0, b0, acc[0][0], 0, 0, 0);
            acc[0][1] = __builtin_amdgcn_mfma_f32_16x16x32_bf16(a0, b1, acc[0][1], 0, 0, 0);
            acc[1][0] = __builtin_amdgcn_mfma_f32_16x16x32_bf16(a1, b0, acc[1][0], 0, 0, 0);
            acc[1][1] = __builtin_amdgcn_mfma_f32_16x16x32_bf16(a1, b1, acc[1][1], 0, 0, 0);
        }
    }

#pragma unroll
    for (int m = 0; m < 2; ++m)
#pragma unroll
        for (int n = 0; n < 2; ++n)
#pragma unroll
            for (int r = 0; r < 4; ++r) {
                const int grow = i0 + mr0 + 16 * m + 4 * lhi + r;
                const int gcol = j0 + nc0 + 16 * n + l15;
                const int b = grow >> 10, s = grow & 1023;
                const int h = gcol >> 6, d = gcol & 63;
                const size_t idx = (((size_t)b * H_ + h) * S_ + s) * DH_ + d;
                const float v = acc[m][n][r];
                if (MODE == 0) {
                    const float base = v + bias[gcol];
                    out0[idx] = f2bf(base + ub[gcol]);
                    out1[idx] = f2bf(base + vb[gcol]);
                } else if (MODE == 1) {
                    out0[idx] = f2bf(v + bias[gcol]);
                } else {
                    out0[idx] = f2bf(v);
                }
            }
}

// ===========================================================================
// Fused score kernel: per 32-row strip of one (b,h):
//   Phase B: R[i0..i0+32, 0..S) = (q+v_bias).p^T via MFMA -> LDS (bf16)
//   Phase C: content = (q+u_bias).k^T via MFMA (regs) + rel-shift gather of R
//            + scale + in-register softmax -> attn (fp32, d_out)
// 512 threads = 8 waves; wave w owns 16-col slice per 128-col chunk.
// shifted[i,j] = R[i, 1023-i+j] (j<=i) ; 0 (j==i+1) ; R[i+1, j-i-2] (j>=i+2)
// ===========================================================================
#define RS 1032   // padded LDS row stride for R (elements)

__global__ __launch_bounds__(512) void score_fused_k(
    const unsigned short* __restrict__ qu_g,  // [B,H,S,DH]
    const unsigned short* __restrict__ qv_g,
    const unsigned short* __restrict__ kb_g,
    const unsigned short* __restrict__ pb_g,
    float* __restrict__ attn)                 // [B,H,S,S]
{
    __shared__ unsigned short Qu[32][72];
    __shared__ unsigned short Aq[48][72];
    __shared__ unsigned short Bb[128][72];
    __shared__ unsigned short Rfl[33 * RS];
    __shared__ float red[32][9];

    const int tid = threadIdx.x;
    const int i0 = blockIdx.x * 32;
    const int bh = blockIdx.y;
    const int w = tid >> 6, lane = tid & 63, l15 = lane & 15, lhi = lane >> 4;

    const unsigned short* qu_b = qu_g + (size_t)bh * S_ * DH_;
    const unsigned short* qv_b = qv_g + (size_t)bh * S_ * DH_;
    const unsigned short* kb_b = kb_g + (size_t)bh * S_ * DH_;
    const unsigned short* pb_b = pb_g + (size_t)bh * S_ * DH_;

    // ---- Phase A: stage A-operand strips ----
    {
        const int r = tid >> 4, dg = (tid & 15) * 4;                  // Qu: 512 slots
        *(uint2*)&Qu[r][dg] = *(const uint2*)&qu_b[(size_t)(i0 + r) * DH_ + dg];
#pragma unroll
        for (int it = 0; it < 2; ++it) {                              // Aq: 768 slots
            const int s = tid + it * 512;
            if (s < 768) {
                const int rr = s >> 4, dgg = (s & 15) * 4;
                const int src = min(i0 + rr, S_ - 1);
                *(uint2*)&Aq[rr][dgg] = *(const uint2*)&qv_b[(size_t)src * DH_ + dgg];
            }
        }
    }

    // ---- Phase B: R strip via MFMA -> Rfl ----
    for (int jc = 0; jc < 8; ++jc) {
        __syncthreads();
#pragma unroll
        for (int it = 0; it < 4; ++it) {                              // 2048 slots
            const int s = tid + it * 512;
            const int rr = s >> 4, dgg = (s & 15) * 4;
            *(uint2*)&Bb[rr][dgg] = *(const uint2*)&pb_b[(size_t)(jc * 128 + rr) * DH_ + dgg];
        }
        __syncthreads();

        f32x4 racc[3] = {};
#pragma unroll
        for (int kk = 0; kk < 2; ++kk) {
            bf16x8 bfr = *(const bf16x8*)&Bb[16 * w + l15][kk * 32 + lhi * 8];
#pragma unroll
            for (int m = 0; m < 3; ++m) {
                bf16x8 a = *(const bf16x8*)&Aq[16 * m + l15][kk * 32 + lhi * 8];
                racc[m] = __builtin_amdgcn_mfma_f32_16x16x32_bf16(a, bfr, racc[m], 0, 0, 0);
            }
        }
#pragma unroll
        for (int m = 0; m < 3; ++m)
#pragma unroll
            for (int r = 0; r < 4; ++r) {
                const int row = 16 * m + 4 * lhi + r;
                if (row < 33)
                    Rfl[row * RS + jc * 128 + 16 * w + l15] = f2bf(racc[m][r]);
            }
    }

    // ---- Phase C: content MFMA into registers ----
    f32x4 acc[8][2] = {};
#pragma unroll
    for (int jc = 0; jc < 8; ++jc) {
        __syncthreads();
#pragma unroll
        for (int it = 0; it < 4; ++it) {
            const int s = tid + it * 512;
            const int rr = s >> 4, dgg = (s & 15) * 4;
            *(uint2*)&Bb[rr][dgg] = *(const uint2*)&kb_b[(size_t)(jc * 128 + rr) * DH_ + dgg];
        }
        __syncthreads();
#pragma unroll
        for (int kk = 0; kk < 2; ++kk) {
            bf16x8 bfr = *(const bf16x8*)&Bb[16 * w + l15][kk * 32 + lhi * 8];
#pragma unroll
            for (int m = 0; m < 2; ++m) {
                bf16x8 a = *(const bf16x8*)&Qu[16 * m + l15][kk * 32 + lhi * 8];
                acc[jc][m] = __builtin_amdgcn_mfma_f32_16x16x32_bf16(a, bfr, acc[jc][m], 0, 0, 0);
            }
        }
    }

    // ---- Epilogue: gather R + scale, then softmax over full rows ----
    float rmax[2][4], rsum[2][4];
#pragma unroll
    for (int m = 0; m < 2; ++m)
#pragma unroll
        for (int r = 0; r < 4; ++r) rmax[m][r] = -3.0e38f;

#pragma unroll
    for (int jc = 0; jc < 8; ++jc)
#pragma unroll
        for (int m = 0; m < 2; ++m)
#pragma unroll
            for (int r = 0; r < 4; ++r) {
                const int il = 16 * m + 4 * lhi + r;
                const int i = i0 + il;
                const int j = jc * 128 + 16 * w + l15;
                float pos = 0.f;
                if (j <= i)          pos = bf2f(Rfl[il * RS + 1023 - i + j]);
                else if (j >= i + 2) pos = bf2f(Rfl[(il + 1) * RS + (j - i - 2)]);
                const float s = (acc[jc][m][r] + pos) * SCALE;
                acc[jc][m][r] = s;
                rmax[m][r] = fmaxf(rmax[m][r], s);
            }

#pragma unroll
    for (int m = 0; m < 2; ++m)
#pragma unroll
        for (int r = 0; r < 4; ++r) {
#pragma unroll
            for (int off = 1; off < 16; off <<= 1)
                rmax[m][r] = fmaxf(rmax[m][r], __shfl_xor(rmax[m][r], off));
        }
    if (l15 == 0) {
#pragma unroll
        for (int m = 0; m < 2; ++m)
#pragma unroll
            for (int r = 0; r < 4; ++r) red[16 * m + 4 * lhi + r][w] = rmax[m][r];
    }
    __syncthreads();
#pragma unroll
    for (int m = 0; m < 2; ++m)
#pragma unroll
        for (int r = 0; r < 4; ++r) {
            const int il = 16 * m + 4 * lhi + r;
            float mx = red[il][0];
#pragma unroll
            for (int ww = 1; ww < 8; ++ww) mx = fmaxf(mx, red[il][ww]);
            rmax[m][r] = mx;
            rsum[m][r] = 0.f;
        }
    __syncthreads();   // red reads done before reuse

#pragma unroll
    for (int jc = 0; jc < 8; ++jc)
#pragma unroll
        for (int m = 0; m < 2; ++m)
#pragma unroll
            for (int r = 0; r < 4; ++r) {
                const float e = __expf(acc[jc][m][r] - rmax[m][r]);
                acc[jc][m][r] = e;
                rsum[m][r] += e;
            }
#pragma unroll
    for (int m = 0; m < 2; ++m)
#pragma unroll
        for (int r = 0; r < 4; ++r) {
#pragma unroll
            for (int off = 1; off < 16; off <<= 1)
                rsum[m][r] += __shfl_xor(rsum[m][r], off);
        }
    if (l15 == 0) {
#pragma unroll
        for (int m = 0; m < 2; ++m)
#pragma unroll
            for (int r = 0; r < 4; ++r) red[16 * m + 4 * lhi + r][w] = rsum[m][r];
    }
    __syncthreads();

    float* attn_b = attn + (size_t)bh * S_ * S_;
#pragma unroll
    for (int m = 0; m < 2; ++m)
#pragma unroll
        for (int r = 0; r < 4; ++r) {
            const int il = 16 * m + 4 * lhi + r;
            float sum = red[il][0];
#pragma unroll
            for (int ww = 1; ww < 8; ++ww) sum += red[il][ww];
            const float inv = 1.f / sum;
#pragma unroll
            for (int jc = 0; jc < 8; ++jc) {
                const int j = jc * 128 + 16 * w + l15;
                attn_b[(size_t)(i0 + il) * S_ + j] = acc[jc][m][r] * inv;
            }
        }
}

// ===========================================================================
extern "C" void kernel_launch(void* const* d_in, const int* in_sizes, int n_in,
                              void* d_out, int out_size, void* d_ws, size_t ws_size,
                              hipStream_t stream)
{
    const float* query = (const float*)d_in[0];
    const float* key_  = (const float*)d_in[1];
    const float* value = (const float*)d_in[2];
    const float* pose  = (const float*)d_in[3];
    const float* Wq = (const float*)d_in[4];
    const float* bq = (const float*)d_in[5];
    const float* Wk = (const float*)d_in[6];
    const float* bk = (const float*)d_in[7];
    const float* Wv = (const float*)d_in[8];
    const float* bv = (const float*)d_in[9];
    const float* Wp = (const float*)d_in[10];
    const float* Wo = (const float*)d_in[11];
    const float* bo = (const float*)d_in[12];
    const float* u_bias = (const float*)d_in[13];
    const float* v_bias = (const float*)d_in[14];

    const size_t NTOK = (size_t)B_ * S_ * D_;   // 2,097,152
    float* out  = (float*)d_out;                // [B,S,D]
    float* attn = (float*)d_out + NTOK;         // [B,H,S,S]

    unsigned short* qu  = (unsigned short*)d_ws;
    unsigned short* qv  = qu + NTOK;
    unsigned short* kbf = qv + NTOK;
    unsigned short* pbf = kbf + NTOK;
    unsigned short* WqT = pbf + NTOK;
    unsigned short* WkT = WqT + 262144;
    unsigned short* WpT = WkT + 262144;
    float* vv  = (float*)(WpT + 262144);        // fp32 [B,S,D]
    float* ctx = vv + NTOK;                     // fp32 [B,S,D]

    const dim3 blk256(256);
    const dim3 gproj(64, 8);

    convert_wt_k<<<dim3(1024, 3), blk256, 0, stream>>>(Wq, Wk, Wp, WqT, WkT, WpT);

    proj_mfma<0><<<gproj, blk256, 0, stream>>>(query, WqT, bq, u_bias, v_bias, qu, qv);
    proj_mfma<1><<<gproj, blk256, 0, stream>>>(key_,  WkT, bk, nullptr, nullptr, kbf, nullptr);
    proj_mfma<2><<<gproj, blk256, 0, stream>>>(pose,  WpT, nullptr, nullptr, nullptr, pbf, nullptr);

    gemm_bias_k<<<gproj, blk256, 0, stream>>>(value, D_, Wv, D_, bv, vv, D_, D_);

    score_fused_k<<<dim3(S_ / 32, B_ * H_), dim3(512), 0, stream>>>(qu, qv, kbf, pbf, attn);

    context_gemm_k<<<dim3(S_ / 64, 1, B_ * H_), blk256, 0, stream>>>(attn, vv, ctx);

    gemm_bias_k<<<gproj, blk256, 0, stream>>>(ctx, D_, Wo, D_, bo, out, D_, D_);
}

// Round 4
// 238.972 us; speedup vs baseline: 4.8424x; 1.6593x over previous
//
#include <hip/hip_runtime.h>

#define B_  4
#define S_  1024
#define D_  512
#define H_  8
#define DH_ 64
#define SCALE 0.044194173824159216f  // 1/sqrt(512)

typedef short bf16x8 __attribute__((ext_vector_type(8)));
typedef float f32x4  __attribute__((ext_vector_type(4)));

__device__ __forceinline__ unsigned short f2bf(float x) {
    union { float f; unsigned int u; } v; v.f = x;
    unsigned int r = v.u + 0x7fffu + ((v.u >> 16) & 1u);
    return (unsigned short)(r >> 16);
}
__device__ __forceinline__ float bf2f(unsigned short h) {
    union { unsigned int u; float f; } v; v.u = ((unsigned int)h) << 16;
    return v.f;
}

// ===========================================================================
// Weight transpose + bf16 convert: T[o,i] = bf16(W[i,o]) for Wq,Wk,Wp,Wv,Wo
// ===========================================================================
__global__ __launch_bounds__(256) void convert_wt_k(
    const float* __restrict__ W0, const float* __restrict__ W1,
    const float* __restrict__ W2, const float* __restrict__ W3,
    const float* __restrict__ W4,
    unsigned short* __restrict__ T0, unsigned short* __restrict__ T1,
    unsigned short* __restrict__ T2, unsigned short* __restrict__ T3,
    unsigned short* __restrict__ T4)
{
    const float* W;
    unsigned short* T;
    switch (blockIdx.y) {
        case 0: W = W0; T = T0; break;
        case 1: W = W1; T = T1; break;
        case 2: W = W2; T = T2; break;
        case 3: W = W3; T = T3; break;
        default: W = W4; T = T4; break;
    }
    const int e = blockIdx.x * 256 + threadIdx.x;   // 512*512 = 262144 total
    const int o = e >> 9, i = e & 511;
    T[(size_t)o * 512 + i] = f2bf(W[(size_t)i * 512 + o]);
}

// ===========================================================================
// bf16 MFMA projection GEMM: C = A @ WT^T (+bias terms)
// MODE 0: q -> qu = bf16(acc+bq+u_bias), qv = bf16(acc+bq+v_bias)  [B,H,S,DH]
// MODE 1: k -> bf16(acc+bk)  [B,H,S,DH]
// MODE 2: p -> bf16(acc)     [B,H,S,DH]
// MODE 3: v -> bf16(acc+bv)  [B,H,DH,S]  (transposed, context B-operand)
// 64x64 tile, BK=64, 4 waves (each a 32x32 quadrant).
// ===========================================================================
template<int MODE>
__global__ __launch_bounds__(256) void proj_mfma(
    const float* __restrict__ A,            // [4096,512] fp32
    const unsigned short* __restrict__ BT,  // [512,512] bf16 (W^T)
    const float* __restrict__ bias,         // [512]
    const float* __restrict__ ub,
    const float* __restrict__ vb,
    unsigned short* __restrict__ out0,
    unsigned short* __restrict__ out1)
{
    __shared__ unsigned short Ab[64][72];
    __shared__ unsigned short Bb[64][72];
    const int tid = threadIdx.x;
    const int i0 = blockIdx.x * 64, j0 = blockIdx.y * 64;
    const int w = tid >> 6, lane = tid & 63, l15 = lane & 15, lhi = lane >> 4;
    const int mr0 = (w >> 1) * 32, nc0 = (w & 1) * 32;
    f32x4 acc[2][2] = {};

    for (int k0 = 0; k0 < 512; k0 += 64) {
        __syncthreads();
#pragma unroll
        for (int it = 0; it < 4; ++it) {            // A: 1024 ushort4 slots (8B each)
            const int s = tid + it * 256;
            const int row = s >> 4, f4 = (s & 15) * 4;
            float4 va = *(const float4*)&A[(size_t)(i0 + row) * 512 + k0 + f4];
            ushort4 hh;
            hh.x = f2bf(va.x); hh.y = f2bf(va.y); hh.z = f2bf(va.z); hh.w = f2bf(va.w);
            *(ushort4*)&Ab[row][f4] = hh;
        }
#pragma unroll
        for (int it = 0; it < 2; ++it) {            // B: 512 slots of 8 shorts (16B each)
            const int s = tid + it * 256;
            const int row = s >> 3, g = (s & 7) * 8;
            *(bf16x8*)&Bb[row][g] = *(const bf16x8*)&BT[(size_t)(j0 + row) * 512 + k0 + g];
        }
        __syncthreads();
#pragma unroll
        for (int kk = 0; kk < 2; ++kk) {
            bf16x8 a0 = *(const bf16x8*)&Ab[mr0 + l15][kk * 32 + lhi * 8];
            bf16x8 a1 = *(const bf16x8*)&Ab[mr0 + 16 + l15][kk * 32 + lhi * 8];
            bf16x8 b0 = *(const bf16x8*)&Bb[nc0 + l15][kk * 32 + lhi * 8];
            bf16x8 b1 = *(const bf16x8*)&Bb[nc0 + 16 + l15][kk * 32 + lhi * 8];
            acc[0][0] = __builtin_amdgcn_mfma_f32_16x16x32_bf16(a0, b0, acc[0][0], 0, 0, 0);
            acc[0][1] = __builtin_amdgcn_mfma_f32_16x16x32_bf16(a0, b1, acc[0][1], 0, 0, 0);
            acc[1][0] = __builtin_amdgcn_mfma_f32_16x16x32_bf16(a1, b0, acc[1][0], 0, 0, 0);
            acc[1][1] = __builtin_amdgcn_mfma_f32_16x16x32_bf16(a1, b1, acc[1][1], 0, 0, 0);
        }
    }

#pragma unroll
    for (int m = 0; m < 2; ++m)
#pragma unroll
        for (int n = 0; n < 2; ++n)
#pragma unroll
            for (int r = 0; r < 4; ++r) {
                const int grow = i0 + mr0 + 16 * m + 4 * lhi + r;
                const int gcol = j0 + nc0 + 16 * n + l15;
                const int b = grow >> 10, s = grow & 1023;
                const int h = gcol >> 6, d = gcol & 63;
                const float v = acc[m][n][r];
                if (MODE == 3) {
                    const size_t idx = (((size_t)(b * H_ + h)) * DH_ + d) * S_ + s;
                    out0[idx] = f2bf(v + bias[gcol]);
                } else {
                    const size_t idx = (((size_t)b * H_ + h) * S_ + s) * DH_ + d;
                    if (MODE == 0) {
                        const float base = v + bias[gcol];
                        out0[idx] = f2bf(base + ub[gcol]);
                        out1[idx] = f2bf(base + vb[gcol]);
                    } else if (MODE == 1) {
                        out0[idx] = f2bf(v + bias[gcol]);
                    } else {
                        out0[idx] = f2bf(v);
                    }
                }
            }
}

// ===========================================================================
// bf16 GEMM with fp32 output: C[4096,512] = A(bf16) @ BT^T (+bias)
// ===========================================================================
__global__ __launch_bounds__(256) void gemm_bf16_k(
    const unsigned short* __restrict__ A,   // [4096,512] bf16
    const unsigned short* __restrict__ BT,  // [512,512] bf16
    const float* __restrict__ bias,
    float* __restrict__ C)                  // [4096,512] fp32
{
    __shared__ unsigned short Ab[64][72];
    __shared__ unsigned short Bb[64][72];
    const int tid = threadIdx.x;
    const int i0 = blockIdx.x * 64, j0 = blockIdx.y * 64;
    const int w = tid >> 6, lane = tid & 63, l15 = lane & 15, lhi = lane >> 4;
    const int mr0 = (w >> 1) * 32, nc0 = (w & 1) * 32;
    f32x4 acc[2][2] = {};

    for (int k0 = 0; k0 < 512; k0 += 64) {
        __syncthreads();
#pragma unroll
        for (int it = 0; it < 2; ++it) {
            const int s = tid + it * 256;
            const int row = s >> 3, g = (s & 7) * 8;
            *(bf16x8*)&Ab[row][g] = *(const bf16x8*)&A[(size_t)(i0 + row) * 512 + k0 + g];
            *(bf16x8*)&Bb[row][g] = *(const bf16x8*)&BT[(size_t)(j0 + row) * 512 + k0 + g];
        }
        __syncthreads();
#pragma unroll
        for (int kk = 0; kk < 2; ++kk) {
            bf16x8 a0 = *(const bf16x8*)&Ab[mr0 + l15][kk * 32 + lhi * 8];
            bf16x8 a1 = *(const bf16x8*)&Ab[mr0 + 16 + l15][kk * 32 + lhi * 8];
            bf16x8 b0 = *(const bf16x8*)&Bb[nc0 + l15][kk * 32 + lhi * 8];
            bf16x8 b1 = *(const bf16x8*)&Bb[nc0 + 16 + l15][kk * 32 + lhi * 8];
            acc[0][0] = __builtin_amdgcn_mfma_f32_16x16x32_bf16(a0, b0, acc[0][0], 0, 0, 0);
            acc[0][1] = __builtin_amdgcn_mfma_f32_16x16x32_bf16(a0, b1, acc[0][1], 0, 0, 0);
            acc[1][0] = __builtin_amdgcn_mfma_f32_16x16x32_bf16(a1, b0, acc[1][0], 0, 0, 0);
            acc[1][1] = __builtin_amdgcn_mfma_f32_16x16x32_bf16(a1, b1, acc[1][1], 0, 0, 0);
        }
    }

#pragma unroll
    for (int m = 0; m < 2; ++m)
#pragma unroll
        for (int n = 0; n < 2; ++n)
#pragma unroll
            for (int r = 0; r < 4; ++r) {
                const int grow = i0 + mr0 + 16 * m + 4 * lhi + r;
                const int gcol = j0 + nc0 + 16 * n + l15;
                C[(size_t)grow * 512 + gcol] = acc[m][n][r] + bias[gcol];
            }
}

// ===========================================================================
// Context GEMM via MFMA: ctx[b,s,h,d] = sum_t attn[b,h,s,t] * v[b,t,h,d]
// A = attn fp32 (d_out) converted to bf16 during staging; B = vT bf16.
// BM=64, BN=64(=DH), BK=64; 4 waves, wave w owns rows [16w,16w+16).
// ===========================================================================
__global__ __launch_bounds__(256) void context_mfma_k(
    const float* __restrict__ attn,         // [B,H,S,S] fp32
    const unsigned short* __restrict__ vT,  // [B,H,DH,S] bf16
    unsigned short* __restrict__ ctx)       // [B,S,D] bf16
{
    __shared__ unsigned short Ab[64][72];
    __shared__ unsigned short Bb[64][72];
    const int tid = threadIdx.x;
    const int i0 = blockIdx.x * 64;
    const int bh = blockIdx.y;
    const int b = bh >> 3, h = bh & 7;
    const int w = tid >> 6, lane = tid & 63, l15 = lane & 15, lhi = lane >> 4;

    const float* attn_b = attn + (size_t)bh * S_ * S_;
    const unsigned short* vT_b = vT + (size_t)bh * DH_ * S_;

    f32x4 acc[4] = {};

    for (int k0 = 0; k0 < S_; k0 += 64) {
        __syncthreads();
#pragma unroll
        for (int it = 0; it < 4; ++it) {            // A: 64x64 fp32 -> bf16 LDS
            const int s = tid + it * 256;           // 1024 slots of 4 floats
            const int row = s >> 4, g = (s & 15) * 4;
            float4 va = *(const float4*)&attn_b[(size_t)(i0 + row) * S_ + k0 + g];
            ushort4 hh;
            hh.x = f2bf(va.x); hh.y = f2bf(va.y); hh.z = f2bf(va.z); hh.w = f2bf(va.w);
            *(ushort4*)&Ab[row][g] = hh;
        }
#pragma unroll
        for (int it = 0; it < 2; ++it) {            // B: 64 d-rows x 64 t
            const int s = tid + it * 256;           // 512 slots of 8 shorts
            const int row = s >> 3, g = (s & 7) * 8;
            *(bf16x8*)&Bb[row][g] = *(const bf16x8*)&vT_b[(size_t)row * S_ + k0 + g];
        }
        __syncthreads();
#pragma unroll
        for (int kk = 0; kk < 2; ++kk) {
            bf16x8 a = *(const bf16x8*)&Ab[16 * w + l15][kk * 32 + lhi * 8];
#pragma unroll
            for (int n = 0; n < 4; ++n) {
                bf16x8 bfr = *(const bf16x8*)&Bb[16 * n + l15][kk * 32 + lhi * 8];
                acc[n] = __builtin_amdgcn_mfma_f32_16x16x32_bf16(a, bfr, acc[n], 0, 0, 0);
            }
        }
    }

#pragma unroll
    for (int n = 0; n < 4; ++n)
#pragma unroll
        for (int r = 0; r < 4; ++r) {
            const int s = i0 + 16 * w + 4 * lhi + r;
            const int d = 16 * n + l15;
            ctx[((size_t)(b * S_ + s)) * D_ + h * DH_ + d] = f2bf(acc[n][r]);
        }
}

// ===========================================================================
// Fused score kernel (unchanged from round 3)
// ===========================================================================
#define RS 1032   // padded LDS row stride for R (elements)

__global__ __launch_bounds__(512) void score_fused_k(
    const unsigned short* __restrict__ qu_g,  // [B,H,S,DH]
    const unsigned short* __restrict__ qv_g,
    const unsigned short* __restrict__ kb_g,
    const unsigned short* __restrict__ pb_g,
    float* __restrict__ attn)                 // [B,H,S,S]
{
    __shared__ unsigned short Qu[32][72];
    __shared__ unsigned short Aq[48][72];
    __shared__ unsigned short Bb[128][72];
    __shared__ unsigned short Rfl[33 * RS];
    __shared__ float red[32][9];

    const int tid = threadIdx.x;
    const int i0 = blockIdx.x * 32;
    const int bh = blockIdx.y;
    const int w = tid >> 6, lane = tid & 63, l15 = lane & 15, lhi = lane >> 4;

    const unsigned short* qu_b = qu_g + (size_t)bh * S_ * DH_;
    const unsigned short* qv_b = qv_g + (size_t)bh * S_ * DH_;
    const unsigned short* kb_b = kb_g + (size_t)bh * S_ * DH_;
    const unsigned short* pb_b = pb_g + (size_t)bh * S_ * DH_;

    {
        const int r = tid >> 4, dg = (tid & 15) * 4;                  // Qu: 512 slots
        *(uint2*)&Qu[r][dg] = *(const uint2*)&qu_b[(size_t)(i0 + r) * DH_ + dg];
#pragma unroll
        for (int it = 0; it < 2; ++it) {                              // Aq: 768 slots
            const int s = tid + it * 512;
            if (s < 768) {
                const int rr = s >> 4, dgg = (s & 15) * 4;
                const int src = min(i0 + rr, S_ - 1);
                *(uint2*)&Aq[rr][dgg] = *(const uint2*)&qv_b[(size_t)src * DH_ + dgg];
            }
        }
    }

    for (int jc = 0; jc < 8; ++jc) {
        __syncthreads();
#pragma unroll
        for (int it = 0; it < 4; ++it) {
            const int s = tid + it * 512;
            const int rr = s >> 4, dgg = (s & 15) * 4;
            *(uint2*)&Bb[rr][dgg] = *(const uint2*)&pb_b[(size_t)(jc * 128 + rr) * DH_ + dgg];
        }
        __syncthreads();

        f32x4 racc[3] = {};
#pragma unroll
        for (int kk = 0; kk < 2; ++kk) {
            bf16x8 bfr = *(const bf16x8*)&Bb[16 * w + l15][kk * 32 + lhi * 8];
#pragma unroll
            for (int m = 0; m < 3; ++m) {
                bf16x8 a = *(const bf16x8*)&Aq[16 * m + l15][kk * 32 + lhi * 8];
                racc[m] = __builtin_amdgcn_mfma_f32_16x16x32_bf16(a, bfr, racc[m], 0, 0, 0);
            }
        }
#pragma unroll
        for (int m = 0; m < 3; ++m)
#pragma unroll
            for (int r = 0; r < 4; ++r) {
                const int row = 16 * m + 4 * lhi + r;
                if (row < 33)
                    Rfl[row * RS + jc * 128 + 16 * w + l15] = f2bf(racc[m][r]);
            }
    }

    f32x4 acc[8][2] = {};
#pragma unroll
    for (int jc = 0; jc < 8; ++jc) {
        __syncthreads();
#pragma unroll
        for (int it = 0; it < 4; ++it) {
            const int s = tid + it * 512;
            const int rr = s >> 4, dgg = (s & 15) * 4;
            *(uint2*)&Bb[rr][dgg] = *(const uint2*)&kb_b[(size_t)(jc * 128 + rr) * DH_ + dgg];
        }
        __syncthreads();
#pragma unroll
        for (int kk = 0; kk < 2; ++kk) {
            bf16x8 bfr = *(const bf16x8*)&Bb[16 * w + l15][kk * 32 + lhi * 8];
#pragma unroll
            for (int m = 0; m < 2; ++m) {
                bf16x8 a = *(const bf16x8*)&Qu[16 * m + l15][kk * 32 + lhi * 8];
                acc[jc][m] = __builtin_amdgcn_mfma_f32_16x16x32_bf16(a, bfr, acc[jc][m], 0, 0, 0);
            }
        }
    }

    float rmax[2][4], rsum[2][4];
#pragma unroll
    for (int m = 0; m < 2; ++m)
#pragma unroll
        for (int r = 0; r < 4; ++r) rmax[m][r] = -3.0e38f;

#pragma unroll
    for (int jc = 0; jc < 8; ++jc)
#pragma unroll
        for (int m = 0; m < 2; ++m)
#pragma unroll
            for (int r = 0; r < 4; ++r) {
                const int il = 16 * m + 4 * lhi + r;
                const int i = i0 + il;
                const int j = jc * 128 + 16 * w + l15;
                float pos = 0.f;
                if (j <= i)          pos = bf2f(Rfl[il * RS + 1023 - i + j]);
                else if (j >= i + 2) pos = bf2f(Rfl[(il + 1) * RS + (j - i - 2)]);
                const float s = (acc[jc][m][r] + pos) * SCALE;
                acc[jc][m][r] = s;
                rmax[m][r] = fmaxf(rmax[m][r], s);
            }

#pragma unroll
    for (int m = 0; m < 2; ++m)
#pragma unroll
        for (int r = 0; r < 4; ++r) {
#pragma unroll
            for (int off = 1; off < 16; off <<= 1)
                rmax[m][r] = fmaxf(rmax[m][r], __shfl_xor(rmax[m][r], off));
        }
    if (l15 == 0) {
#pragma unroll
        for (int m = 0; m < 2; ++m)
#pragma unroll
            for (int r = 0; r < 4; ++r) red[16 * m + 4 * lhi + r][w] = rmax[m][r];
    }
    __syncthreads();
#pragma unroll
    for (int m = 0; m < 2; ++m)
#pragma unroll
        for (int r = 0; r < 4; ++r) {
            const int il = 16 * m + 4 * lhi + r;
            float mx = red[il][0];
#pragma unroll
            for (int ww = 1; ww < 8; ++ww) mx = fmaxf(mx, red[il][ww]);
            rmax[m][r] = mx;
            rsum[m][r] = 0.f;
        }
    __syncthreads();

#pragma unroll
    for (int jc = 0; jc < 8; ++jc)
#pragma unroll
        for (int m = 0; m < 2; ++m)
#pragma unroll
            for (int r = 0; r < 4; ++r) {
                const float e = __expf(acc[jc][m][r] - rmax[m][r]);
                acc[jc][m][r] = e;
                rsum[m][r] += e;
            }
#pragma unroll
    for (int m = 0; m < 2; ++m)
#pragma unroll
        for (int r = 0; r < 4; ++r) {
#pragma unroll
            for (int off = 1; off < 16; off <<= 1)
                rsum[m][r] += __shfl_xor(rsum[m][r], off);
        }
    if (l15 == 0) {
#pragma unroll
        for (int m = 0; m < 2; ++m)
#pragma unroll
            for (int r = 0; r < 4; ++r) red[16 * m + 4 * lhi + r][w] = rsum[m][r];
    }
    __syncthreads();

    float* attn_b = attn + (size_t)bh * S_ * S_;
#pragma unroll
    for (int m = 0; m < 2; ++m)
#pragma unroll
        for (int r = 0; r < 4; ++r) {
            const int il = 16 * m + 4 * lhi + r;
            float sum = red[il][0];
#pragma unroll
            for (int ww = 1; ww < 8; ++ww) sum += red[il][ww];
            const float inv = 1.f / sum;
#pragma unroll
            for (int jc = 0; jc < 8; ++jc) {
                const int j = jc * 128 + 16 * w + l15;
                attn_b[(size_t)(i0 + il) * S_ + j] = acc[jc][m][r] * inv;
            }
        }
}

// ===========================================================================
extern "C" void kernel_launch(void* const* d_in, const int* in_sizes, int n_in,
                              void* d_out, int out_size, void* d_ws, size_t ws_size,
                              hipStream_t stream)
{
    const float* query = (const float*)d_in[0];
    const float* key_  = (const float*)d_in[1];
    const float* value = (const float*)d_in[2];
    const float* pose  = (const float*)d_in[3];
    const float* Wq = (const float*)d_in[4];
    const float* bq = (const float*)d_in[5];
    const float* Wk = (const float*)d_in[6];
    const float* bk = (const float*)d_in[7];
    const float* Wv = (const float*)d_in[8];
    const float* bv = (const float*)d_in[9];
    const float* Wp = (const float*)d_in[10];
    const float* Wo = (const float*)d_in[11];
    const float* bo = (const float*)d_in[12];
    const float* u_bias = (const float*)d_in[13];
    const float* v_bias = (const float*)d_in[14];

    const size_t NTOK = (size_t)B_ * S_ * D_;   // 2,097,152
    float* out  = (float*)d_out;                // [B,S,D]
    float* attn = (float*)d_out + NTOK;         // [B,H,S,S]

    unsigned short* qu  = (unsigned short*)d_ws;
    unsigned short* qv  = qu + NTOK;
    unsigned short* kbf = qv + NTOK;
    unsigned short* pbf = kbf + NTOK;
    unsigned short* WqT = pbf + NTOK;
    unsigned short* WkT = WqT + 262144;
    unsigned short* WpT = WkT + 262144;
    unsigned short* WvT = WpT + 262144;
    unsigned short* WoT = WvT + 262144;
    unsigned short* vT  = WoT + 262144;         // [B,H,DH,S] bf16
    unsigned short* ctx = vT + NTOK;            // [B,S,D] bf16

    const dim3 blk256(256);
    const dim3 gproj(64, 8);

    convert_wt_k<<<dim3(1024, 5), blk256, 0, stream>>>(Wq, Wk, Wp, Wv, Wo,
                                                       WqT, WkT, WpT, WvT, WoT);

    proj_mfma<0><<<gproj, blk256, 0, stream>>>(query, WqT, bq, u_bias, v_bias, qu, qv);
    proj_mfma<1><<<gproj, blk256, 0, stream>>>(key_,  WkT, bk, nullptr, nullptr, kbf, nullptr);
    proj_mfma<2><<<gproj, blk256, 0, stream>>>(pose,  WpT, nullptr, nullptr, nullptr, pbf, nullptr);
    proj_mfma<3><<<gproj, blk256, 0, stream>>>(value, WvT, bv, nullptr, nullptr, vT, nullptr);

    score_fused_k<<<dim3(S_ / 32, B_ * H_), dim3(512), 0, stream>>>(qu, qv, kbf, pbf, attn);

    context_mfma_k<<<dim3(S_ / 64, B_ * H_), blk256, 0, stream>>>(attn, vT, ctx);

    gemm_bf16_k<<<gproj, blk256, 0, stream>>>(ctx, WoT, bo, out);
}

// Round 5
// 201.005 us; speedup vs baseline: 5.7571x; 1.1889x over previous
//
#include <hip/hip_runtime.h>

#define B_  4
#define S_  1024
#define D_  512
#define H_  8
#define DH_ 64
#define SCALE 0.044194173824159216f  // 1/sqrt(512)

typedef short bf16x8 __attribute__((ext_vector_type(8)));
typedef float f32x4  __attribute__((ext_vector_type(4)));

__device__ __forceinline__ unsigned short f2bf(float x) {
    union { float f; unsigned int u; } v; v.f = x;
    unsigned int r = v.u + 0x7fffu + ((v.u >> 16) & 1u);
    return (unsigned short)(r >> 16);
}
__device__ __forceinline__ float bf2f(unsigned short h) {
    union { unsigned int u; float f; } v; v.u = ((unsigned int)h) << 16;
    return v.f;
}

// ===========================================================================
// Weight transpose + bf16 convert: T[o,i] = bf16(W[i,o]) for Wq,Wk,Wp,Wv,Wo
// ===========================================================================
__global__ __launch_bounds__(256) void convert_wt_k(
    const float* __restrict__ W0, const float* __restrict__ W1,
    const float* __restrict__ W2, const float* __restrict__ W3,
    const float* __restrict__ W4,
    unsigned short* __restrict__ T0, unsigned short* __restrict__ T1,
    unsigned short* __restrict__ T2, unsigned short* __restrict__ T3,
    unsigned short* __restrict__ T4)
{
    const float* W;
    unsigned short* T;
    switch (blockIdx.y) {
        case 0: W = W0; T = T0; break;
        case 1: W = W1; T = T1; break;
        case 2: W = W2; T = T2; break;
        case 3: W = W3; T = T3; break;
        default: W = W4; T = T4; break;
    }
    const int e = blockIdx.x * 256 + threadIdx.x;   // 512*512 = 262144 total
    const int o = e >> 9, i = e & 511;
    T[(size_t)o * 512 + i] = f2bf(W[(size_t)i * 512 + o]);
}

// ===========================================================================
// bf16 MFMA projection GEMM: C = A @ WT^T (+bias terms)
// MODE 0: q -> qu = bf16(acc+bq+u_bias), qv = bf16(acc+bq+v_bias)  [B,H,S,DH]
// MODE 1: k -> bf16(acc+bk)  [B,H,S,DH]
// MODE 2: p -> bf16(acc)     [B,H,S,DH]
// MODE 3: v -> bf16(acc+bv)  [B,H,DH,S]  (transposed, context B-operand)
// ===========================================================================
template<int MODE>
__global__ __launch_bounds__(256) void proj_mfma(
    const float* __restrict__ A,            // [4096,512] fp32
    const unsigned short* __restrict__ BT,  // [512,512] bf16 (W^T)
    const float* __restrict__ bias,         // [512]
    const float* __restrict__ ub,
    const float* __restrict__ vb,
    unsigned short* __restrict__ out0,
    unsigned short* __restrict__ out1)
{
    __shared__ unsigned short Ab[64][72];
    __shared__ unsigned short Bb[64][72];
    const int tid = threadIdx.x;
    const int i0 = blockIdx.x * 64, j0 = blockIdx.y * 64;
    const int w = tid >> 6, lane = tid & 63, l15 = lane & 15, lhi = lane >> 4;
    const int mr0 = (w >> 1) * 32, nc0 = (w & 1) * 32;
    f32x4 acc[2][2] = {};

    for (int k0 = 0; k0 < 512; k0 += 64) {
        __syncthreads();
#pragma unroll
        for (int it = 0; it < 4; ++it) {            // A: 1024 ushort4 slots (8B each)
            const int s = tid + it * 256;
            const int row = s >> 4, f4 = (s & 15) * 4;
            float4 va = *(const float4*)&A[(size_t)(i0 + row) * 512 + k0 + f4];
            ushort4 hh;
            hh.x = f2bf(va.x); hh.y = f2bf(va.y); hh.z = f2bf(va.z); hh.w = f2bf(va.w);
            *(ushort4*)&Ab[row][f4] = hh;
        }
#pragma unroll
        for (int it = 0; it < 2; ++it) {            // B: 512 slots of 8 shorts (16B each)
            const int s = tid + it * 256;
            const int row = s >> 3, g = (s & 7) * 8;
            *(bf16x8*)&Bb[row][g] = *(const bf16x8*)&BT[(size_t)(j0 + row) * 512 + k0 + g];
        }
        __syncthreads();
#pragma unroll
        for (int kk = 0; kk < 2; ++kk) {
            bf16x8 a0 = *(const bf16x8*)&Ab[mr0 + l15][kk * 32 + lhi * 8];
            bf16x8 a1 = *(const bf16x8*)&Ab[mr0 + 16 + l15][kk * 32 + lhi * 8];
            bf16x8 b0 = *(const bf16x8*)&Bb[nc0 + l15][kk * 32 + lhi * 8];
            bf16x8 b1 = *(const bf16x8*)&Bb[nc0 + 16 + l15][kk * 32 + lhi * 8];
            acc[0][0] = __builtin_amdgcn_mfma_f32_16x16x32_bf16(a0, b0, acc[0][0], 0, 0, 0);
            acc[0][1] = __builtin_amdgcn_mfma_f32_16x16x32_bf16(a0, b1, acc[0][1], 0, 0, 0);
            acc[1][0] = __builtin_amdgcn_mfma_f32_16x16x32_bf16(a1, b0, acc[1][0], 0, 0, 0);
            acc[1][1] = __builtin_amdgcn_mfma_f32_16x16x32_bf16(a1, b1, acc[1][1], 0, 0, 0);
        }
    }

#pragma unroll
    for (int m = 0; m < 2; ++m)
#pragma unroll
        for (int n = 0; n < 2; ++n)
#pragma unroll
            for (int r = 0; r < 4; ++r) {
                const int grow = i0 + mr0 + 16 * m + 4 * lhi + r;
                const int gcol = j0 + nc0 + 16 * n + l15;
                const int b = grow >> 10, s = grow & 1023;
                const int h = gcol >> 6, d = gcol & 63;
                const float v = acc[m][n][r];
                if (MODE == 3) {
                    const size_t idx = (((size_t)(b * H_ + h)) * DH_ + d) * S_ + s;
                    out0[idx] = f2bf(v + bias[gcol]);
                } else {
                    const size_t idx = (((size_t)b * H_ + h) * S_ + s) * DH_ + d;
                    if (MODE == 0) {
                        const float base = v + bias[gcol];
                        out0[idx] = f2bf(base + ub[gcol]);
                        out1[idx] = f2bf(base + vb[gcol]);
                    } else if (MODE == 1) {
                        out0[idx] = f2bf(v + bias[gcol]);
                    } else {
                        out0[idx] = f2bf(v);
                    }
                }
            }
}

// ===========================================================================
// bf16 GEMM with fp32 output: C[4096,512] = A(bf16) @ BT^T (+bias)
// ===========================================================================
__global__ __launch_bounds__(256) void gemm_bf16_k(
    const unsigned short* __restrict__ A,   // [4096,512] bf16
    const unsigned short* __restrict__ BT,  // [512,512] bf16
    const float* __restrict__ bias,
    float* __restrict__ C)                  // [4096,512] fp32
{
    __shared__ unsigned short Ab[64][72];
    __shared__ unsigned short Bb[64][72];
    const int tid = threadIdx.x;
    const int i0 = blockIdx.x * 64, j0 = blockIdx.y * 64;
    const int w = tid >> 6, lane = tid & 63, l15 = lane & 15, lhi = lane >> 4;
    const int mr0 = (w >> 1) * 32, nc0 = (w & 1) * 32;
    f32x4 acc[2][2] = {};

    for (int k0 = 0; k0 < 512; k0 += 64) {
        __syncthreads();
#pragma unroll
        for (int it = 0; it < 2; ++it) {
            const int s = tid + it * 256;
            const int row = s >> 3, g = (s & 7) * 8;
            *(bf16x8*)&Ab[row][g] = *(const bf16x8*)&A[(size_t)(i0 + row) * 512 + k0 + g];
            *(bf16x8*)&Bb[row][g] = *(const bf16x8*)&BT[(size_t)(j0 + row) * 512 + k0 + g];
        }
        __syncthreads();
#pragma unroll
        for (int kk = 0; kk < 2; ++kk) {
            bf16x8 a0 = *(const bf16x8*)&Ab[mr0 + l15][kk * 32 + lhi * 8];
            bf16x8 a1 = *(const bf16x8*)&Ab[mr0 + 16 + l15][kk * 32 + lhi * 8];
            bf16x8 b0 = *(const bf16x8*)&Bb[nc0 + l15][kk * 32 + lhi * 8];
            bf16x8 b1 = *(const bf16x8*)&Bb[nc0 + 16 + l15][kk * 32 + lhi * 8];
            acc[0][0] = __builtin_amdgcn_mfma_f32_16x16x32_bf16(a0, b0, acc[0][0], 0, 0, 0);
            acc[0][1] = __builtin_amdgcn_mfma_f32_16x16x32_bf16(a0, b1, acc[0][1], 0, 0, 0);
            acc[1][0] = __builtin_amdgcn_mfma_f32_16x16x32_bf16(a1, b0, acc[1][0], 0, 0, 0);
            acc[1][1] = __builtin_amdgcn_mfma_f32_16x16x32_bf16(a1, b1, acc[1][1], 0, 0, 0);
        }
    }

#pragma unroll
    for (int m = 0; m < 2; ++m)
#pragma unroll
        for (int n = 0; n < 2; ++n)
#pragma unroll
            for (int r = 0; r < 4; ++r) {
                const int grow = i0 + mr0 + 16 * m + 4 * lhi + r;
                const int gcol = j0 + nc0 + 16 * n + l15;
                C[(size_t)grow * 512 + gcol] = acc[m][n][r] + bias[gcol];
            }
}

// ===========================================================================
// Context GEMM via MFMA: ctx[b,s,h,d] = sum_t attn[b,h,s,t] * v[b,t,h,d]
// ===========================================================================
__global__ __launch_bounds__(256) void context_mfma_k(
    const float* __restrict__ attn,         // [B,H,S,S] fp32
    const unsigned short* __restrict__ vT,  // [B,H,DH,S] bf16
    unsigned short* __restrict__ ctx)       // [B,S,D] bf16
{
    __shared__ unsigned short Ab[64][72];
    __shared__ unsigned short Bb[64][72];
    const int tid = threadIdx.x;
    const int i0 = blockIdx.x * 64;
    const int bh = blockIdx.y;
    const int b = bh >> 3, h = bh & 7;
    const int w = tid >> 6, lane = tid & 63, l15 = lane & 15, lhi = lane >> 4;

    const float* attn_b = attn + (size_t)bh * S_ * S_;
    const unsigned short* vT_b = vT + (size_t)bh * DH_ * S_;

    f32x4 acc[4] = {};

    for (int k0 = 0; k0 < S_; k0 += 64) {
        __syncthreads();
#pragma unroll
        for (int it = 0; it < 4; ++it) {            // A: 64x64 fp32 -> bf16 LDS
            const int s = tid + it * 256;
            const int row = s >> 4, g = (s & 15) * 4;
            float4 va = *(const float4*)&attn_b[(size_t)(i0 + row) * S_ + k0 + g];
            ushort4 hh;
            hh.x = f2bf(va.x); hh.y = f2bf(va.y); hh.z = f2bf(va.z); hh.w = f2bf(va.w);
            *(ushort4*)&Ab[row][g] = hh;
        }
#pragma unroll
        for (int it = 0; it < 2; ++it) {            // B: 64 d-rows x 64 t
            const int s = tid + it * 256;
            const int row = s >> 3, g = (s & 7) * 8;
            *(bf16x8*)&Bb[row][g] = *(const bf16x8*)&vT_b[(size_t)row * S_ + k0 + g];
        }
        __syncthreads();
#pragma unroll
        for (int kk = 0; kk < 2; ++kk) {
            bf16x8 a = *(const bf16x8*)&Ab[16 * w + l15][kk * 32 + lhi * 8];
#pragma unroll
            for (int n = 0; n < 4; ++n) {
                bf16x8 bfr = *(const bf16x8*)&Bb[16 * n + l15][kk * 32 + lhi * 8];
                acc[n] = __builtin_amdgcn_mfma_f32_16x16x32_bf16(a, bfr, acc[n], 0, 0, 0);
            }
        }
    }

#pragma unroll
    for (int n = 0; n < 4; ++n)
#pragma unroll
        for (int r = 0; r < 4; ++r) {
            const int s = i0 + 16 * w + 4 * lhi + r;
            const int d = 16 * n + l15;
            ctx[((size_t)(b * S_ + s)) * D_ + h * DH_ + d] = f2bf(acc[n][r]);
        }
}

// ===========================================================================
// Fused score kernel, QBLK=16 rows/block, 2 blocks/CU, reg-staged prefetch.
// Per jc chunk (128 cols): stage k+p tiles together, MFMA pos (-> Rfl LDS)
// and content (-> regs); epilogue gathers rel-shift, softmax, writes attn.
// shifted[i,j] = R[i, 1023-i+j] (j<=i) ; 0 (j==i+1) ; R[i+1, j-i-2] (j>=i+2)
// LDS total ~79.4 KB -> 2 blocks/CU.
// ===========================================================================
#define RS 1032   // padded LDS row stride for R (shorts)
#define QBLK 16

__global__ __launch_bounds__(512, 4) void score_fused_k(
    const unsigned short* __restrict__ qu_g,  // [B,H,S,DH]
    const unsigned short* __restrict__ qv_g,
    const unsigned short* __restrict__ kb_g,
    const unsigned short* __restrict__ pb_g,
    float* __restrict__ attn)                 // [B,H,S,S]
{
    __shared__ unsigned short Qu[16][72];
    __shared__ unsigned short Aq[32][72];
    __shared__ unsigned short Kb[128][72];
    __shared__ unsigned short Pb[128][72];
    __shared__ unsigned short Rfl[17 * RS];
    __shared__ float red[16][9];

    const int tid = threadIdx.x;
    const int i0 = blockIdx.x * QBLK;
    const int bh = blockIdx.y;
    const int w = tid >> 6, lane = tid & 63, l15 = lane & 15, lhi = lane >> 4;

    const unsigned short* qu_b = qu_g + (size_t)bh * S_ * DH_;
    const unsigned short* qv_b = qv_g + (size_t)bh * S_ * DH_;
    const unsigned short* kb_b = kb_g + (size_t)bh * S_ * DH_;
    const unsigned short* pb_b = pb_g + (size_t)bh * S_ * DH_;

    // ---- stage A-operands (one-time) ----
    if (tid < 128) {                       // Qu: 16 rows x 8 slots of 16B
        const int r = tid >> 3, seg = (tid & 7) * 8;
        *(bf16x8*)&Qu[r][seg] = *(const bf16x8*)&qu_b[(size_t)(i0 + r) * DH_ + seg];
    }
    if (tid < 256) {                       // Aq: 32 rows (clamped; rows >16 unused garbage-safe)
        const int r = tid >> 3, seg = (tid & 7) * 8;
        const int src = min(i0 + r, S_ - 1);
        *(bf16x8*)&Aq[r][seg] = *(const bf16x8*)&qv_b[(size_t)src * DH_ + seg];
    }

    // ---- main loop: 8 chunks of 128 cols, reg-staged prefetch ----
    bf16x8 kreg[2], preg[2];
#pragma unroll
    for (int it = 0; it < 2; ++it) {       // prologue: load jc=0
        const int s = tid + it * 512;
        const int row = s >> 3, seg = (s & 7) * 8;
        kreg[it] = *(const bf16x8*)&kb_b[(size_t)row * DH_ + seg];
        preg[it] = *(const bf16x8*)&pb_b[(size_t)row * DH_ + seg];
    }

    f32x4 acc[8] = {};
    for (int jc = 0; jc < 8; ++jc) {
        __syncthreads();                   // prior MFMA readers done
#pragma unroll
        for (int it = 0; it < 2; ++it) {
            const int s = tid + it * 512;
            const int row = s >> 3, seg = (s & 7) * 8;
            *(bf16x8*)&Kb[row][seg] = kreg[it];
            *(bf16x8*)&Pb[row][seg] = preg[it];
        }
        if (jc < 7) {
#pragma unroll
            for (int it = 0; it < 2; ++it) {   // prefetch next chunk into regs
                const int s = tid + it * 512;
                const int row = (jc + 1) * 128 + (s >> 3), seg = (s & 7) * 8;
                kreg[it] = *(const bf16x8*)&kb_b[(size_t)row * DH_ + seg];
                preg[it] = *(const bf16x8*)&pb_b[(size_t)row * DH_ + seg];
            }
        }
        __syncthreads();                   // tiles ready

        f32x4 racc[2] = {};
#pragma unroll
        for (int kk = 0; kk < 2; ++kk) {
            bf16x8 pfr = *(const bf16x8*)&Pb[16 * w + l15][kk * 32 + lhi * 8];
            bf16x8 kfr = *(const bf16x8*)&Kb[16 * w + l15][kk * 32 + lhi * 8];
            bf16x8 aq0 = *(const bf16x8*)&Aq[l15][kk * 32 + lhi * 8];
            bf16x8 aq1 = *(const bf16x8*)&Aq[16 + l15][kk * 32 + lhi * 8];
            bf16x8 qf  = *(const bf16x8*)&Qu[l15][kk * 32 + lhi * 8];
            racc[0] = __builtin_amdgcn_mfma_f32_16x16x32_bf16(aq0, pfr, racc[0], 0, 0, 0);
            racc[1] = __builtin_amdgcn_mfma_f32_16x16x32_bf16(aq1, pfr, racc[1], 0, 0, 0);
            acc[jc] = __builtin_amdgcn_mfma_f32_16x16x32_bf16(qf,  kfr, acc[jc], 0, 0, 0);
        }
#pragma unroll
        for (int m = 0; m < 2; ++m)
#pragma unroll
            for (int r = 0; r < 4; ++r) {
                const int row = 16 * m + 4 * lhi + r;
                if (row < 17)
                    Rfl[row * RS + jc * 128 + 16 * w + l15] = f2bf(racc[m][r]);
            }
    }
    __syncthreads();                       // Rfl complete

    // ---- epilogue: rel-shift gather + scale + softmax + write ----
    const int il = 4 * lhi;                // + r
    float rmax[4], rsum[4];
#pragma unroll
    for (int r = 0; r < 4; ++r) rmax[r] = -3.0e38f;

#pragma unroll
    for (int jc = 0; jc < 8; ++jc)
#pragma unroll
        for (int r = 0; r < 4; ++r) {
            const int row = il + r;
            const int i = i0 + row;
            const int j = jc * 128 + 16 * w + l15;
            float pos = 0.f;
            if (j <= i)          pos = bf2f(Rfl[row * RS + 1023 - i + j]);
            else if (j >= i + 2) pos = bf2f(Rfl[(row + 1) * RS + (j - i - 2)]);
            const float s = (acc[jc][r] + pos) * SCALE;
            acc[jc][r] = s;
            rmax[r] = fmaxf(rmax[r], s);
        }

#pragma unroll
    for (int r = 0; r < 4; ++r)
#pragma unroll
        for (int off = 1; off < 16; off <<= 1)
            rmax[r] = fmaxf(rmax[r], __shfl_xor(rmax[r], off));
    if (l15 == 0)
#pragma unroll
        for (int r = 0; r < 4; ++r) red[il + r][w] = rmax[r];
    __syncthreads();
#pragma unroll
    for (int r = 0; r < 4; ++r) {
        float mx = red[il + r][0];
#pragma unroll
        for (int ww = 1; ww < 8; ++ww) mx = fmaxf(mx, red[il + r][ww]);
        rmax[r] = mx;
        rsum[r] = 0.f;
    }
    __syncthreads();                       // red reads done before reuse

#pragma unroll
    for (int jc = 0; jc < 8; ++jc)
#pragma unroll
        for (int r = 0; r < 4; ++r) {
            const float e = __expf(acc[jc][r] - rmax[r]);
            acc[jc][r] = e;
            rsum[r] += e;
        }
#pragma unroll
    for (int r = 0; r < 4; ++r)
#pragma unroll
        for (int off = 1; off < 16; off <<= 1)
            rsum[r] += __shfl_xor(rsum[r], off);
    if (l15 == 0)
#pragma unroll
        for (int r = 0; r < 4; ++r) red[il + r][w] = rsum[r];
    __syncthreads();

    float* attn_b = attn + (size_t)bh * S_ * S_;
#pragma unroll
    for (int r = 0; r < 4; ++r) {
        float sum = red[il + r][0];
#pragma unroll
        for (int ww = 1; ww < 8; ++ww) sum += red[il + r][ww];
        const float inv = 1.f / sum;
#pragma unroll
        for (int jc = 0; jc < 8; ++jc) {
            const int j = jc * 128 + 16 * w + l15;
            attn_b[(size_t)(i0 + il + r) * S_ + j] = acc[jc][r] * inv;
        }
    }
}

// ===========================================================================
extern "C" void kernel_launch(void* const* d_in, const int* in_sizes, int n_in,
                              void* d_out, int out_size, void* d_ws, size_t ws_size,
                              hipStream_t stream)
{
    const float* query = (const float*)d_in[0];
    const float* key_  = (const float*)d_in[1];
    const float* value = (const float*)d_in[2];
    const float* pose  = (const float*)d_in[3];
    const float* Wq = (const float*)d_in[4];
    const float* bq = (const float*)d_in[5];
    const float* Wk = (const float*)d_in[6];
    const float* bk = (const float*)d_in[7];
    const float* Wv = (const float*)d_in[8];
    const float* bv = (const float*)d_in[9];
    const float* Wp = (const float*)d_in[10];
    const float* Wo = (const float*)d_in[11];
    const float* bo = (const float*)d_in[12];
    const float* u_bias = (const float*)d_in[13];
    const float* v_bias = (const float*)d_in[14];

    const size_t NTOK = (size_t)B_ * S_ * D_;   // 2,097,152
    float* out  = (float*)d_out;                // [B,S,D]
    float* attn = (float*)d_out + NTOK;         // [B,H,S,S]

    unsigned short* qu  = (unsigned short*)d_ws;
    unsigned short* qv  = qu + NTOK;
    unsigned short* kbf = qv + NTOK;
    unsigned short* pbf = kbf + NTOK;
    unsigned short* WqT = pbf + NTOK;
    unsigned short* WkT = WqT + 262144;
    unsigned short* WpT = WkT + 262144;
    unsigned short* WvT = WpT + 262144;
    unsigned short* WoT = WvT + 262144;
    unsigned short* vT  = WoT + 262144;         // [B,H,DH,S] bf16
    unsigned short* ctx = vT + NTOK;            // [B,S,D] bf16

    const dim3 blk256(256);
    const dim3 gproj(64, 8);

    convert_wt_k<<<dim3(1024, 5), blk256, 0, stream>>>(Wq, Wk, Wp, Wv, Wo,
                                                       WqT, WkT, WpT, WvT, WoT);

    proj_mfma<0><<<gproj, blk256, 0, stream>>>(query, WqT, bq, u_bias, v_bias, qu, qv);
    proj_mfma<1><<<gproj, blk256, 0, stream>>>(key_,  WkT, bk, nullptr, nullptr, kbf, nullptr);
    proj_mfma<2><<<gproj, blk256, 0, stream>>>(pose,  WpT, nullptr, nullptr, nullptr, pbf, nullptr);
    proj_mfma<3><<<gproj, blk256, 0, stream>>>(value, WvT, bv, nullptr, nullptr, vT, nullptr);

    score_fused_k<<<dim3(S_ / QBLK, B_ * H_), dim3(512), 0, stream>>>(qu, qv, kbf, pbf, attn);

    context_mfma_k<<<dim3(S_ / 64, B_ * H_), blk256, 0, stream>>>(attn, vT, ctx);

    gemm_bf16_k<<<gproj, blk256, 0, stream>>>(ctx, WoT, bo, out);
}

// Round 6
// 138.010 us; speedup vs baseline: 8.3849x; 1.4565x over previous
//
#include <hip/hip_runtime.h>

#define B_  4
#define S_  1024
#define D_  512
#define H_  8
#define DH_ 64
#define SCALE 0.044194173824159216f  // 1/sqrt(512)

typedef short bf16x8 __attribute__((ext_vector_type(8)));
typedef float f32x4  __attribute__((ext_vector_type(4)));

__device__ __forceinline__ unsigned short f2bf(float x) {
    union { float f; unsigned int u; } v; v.f = x;
    unsigned int r = v.u + 0x7fffu + ((v.u >> 16) & 1u);
    return (unsigned short)(r >> 16);
}
__device__ __forceinline__ float bf2f(unsigned short h) {
    union { unsigned int u; float f; } v; v.u = ((unsigned int)h) << 16;
    return v.f;
}

// ===========================================================================
// Weight transpose + bf16 convert: T[o,i] = bf16(W[i,o]) for Wq,Wk,Wp,Wv,Wo
// ===========================================================================
__global__ __launch_bounds__(256) void convert_wt_k(
    const float* __restrict__ W0, const float* __restrict__ W1,
    const float* __restrict__ W2, const float* __restrict__ W3,
    const float* __restrict__ W4,
    unsigned short* __restrict__ T0, unsigned short* __restrict__ T1,
    unsigned short* __restrict__ T2, unsigned short* __restrict__ T3,
    unsigned short* __restrict__ T4)
{
    const float* W;
    unsigned short* T;
    switch (blockIdx.y) {
        case 0: W = W0; T = T0; break;
        case 1: W = W1; T = T1; break;
        case 2: W = W2; T = T2; break;
        case 3: W = W3; T = T3; break;
        default: W = W4; T = T4; break;
    }
    const int e = blockIdx.x * 256 + threadIdx.x;   // 512*512 = 262144 total
    const int o = e >> 9, i = e & 511;
    T[(size_t)o * 512 + i] = f2bf(W[(size_t)i * 512 + o]);
}

// ===========================================================================
// All four input projections in one launch (blockIdx.z = mode).
// mode 0: q -> qu = bf16(acc+bq+u_bias), qv = bf16(acc+bq+v_bias)  [B,H,S,DH]
// mode 1: k -> bf16(acc+bk)  [B,H,S,DH]
// mode 2: p -> bf16(acc)     [B,H,S,DH]
// mode 3: v -> bf16(acc+bv)  [B,H,DH,S]  (transposed, PV B-operand)
// ===========================================================================
__global__ __launch_bounds__(256) void proj_all_k(
    const float* __restrict__ Aq_, const float* __restrict__ Ak_,
    const float* __restrict__ Ap_, const float* __restrict__ Av_,
    const unsigned short* __restrict__ WqT, const unsigned short* __restrict__ WkT,
    const unsigned short* __restrict__ WpT, const unsigned short* __restrict__ WvT,
    const float* __restrict__ bq, const float* __restrict__ bk,
    const float* __restrict__ bv,
    const float* __restrict__ ub, const float* __restrict__ vb,
    unsigned short* __restrict__ qu, unsigned short* __restrict__ qv,
    unsigned short* __restrict__ kbf, unsigned short* __restrict__ pbf,
    unsigned short* __restrict__ vT)
{
    __shared__ unsigned short Ab[64][72];
    __shared__ unsigned short Bb[64][72];
    const int mode = blockIdx.z;
    const float* A;
    const unsigned short* BT;
    switch (mode) {
        case 0: A = Aq_; BT = WqT; break;
        case 1: A = Ak_; BT = WkT; break;
        case 2: A = Ap_; BT = WpT; break;
        default: A = Av_; BT = WvT; break;
    }
    const int tid = threadIdx.x;
    const int i0 = blockIdx.x * 64, j0 = blockIdx.y * 64;
    const int w = tid >> 6, lane = tid & 63, l15 = lane & 15, lhi = lane >> 4;
    const int mr0 = (w >> 1) * 32, nc0 = (w & 1) * 32;
    f32x4 acc[2][2] = {};

    for (int k0 = 0; k0 < 512; k0 += 64) {
        __syncthreads();
#pragma unroll
        for (int it = 0; it < 4; ++it) {            // A: 1024 ushort4 slots (8B each)
            const int s = tid + it * 256;
            const int row = s >> 4, f4 = (s & 15) * 4;
            float4 va = *(const float4*)&A[(size_t)(i0 + row) * 512 + k0 + f4];
            ushort4 hh;
            hh.x = f2bf(va.x); hh.y = f2bf(va.y); hh.z = f2bf(va.z); hh.w = f2bf(va.w);
            *(ushort4*)&Ab[row][f4] = hh;
        }
#pragma unroll
        for (int it = 0; it < 2; ++it) {            // B: 512 slots of 8 shorts (16B each)
            const int s = tid + it * 256;
            const int row = s >> 3, g = (s & 7) * 8;
            *(bf16x8*)&Bb[row][g] = *(const bf16x8*)&BT[(size_t)(j0 + row) * 512 + k0 + g];
        }
        __syncthreads();
#pragma unroll
        for (int kk = 0; kk < 2; ++kk) {
            bf16x8 a0 = *(const bf16x8*)&Ab[mr0 + l15][kk * 32 + lhi * 8];
            bf16x8 a1 = *(const bf16x8*)&Ab[mr0 + 16 + l15][kk * 32 + lhi * 8];
            bf16x8 b0 = *(const bf16x8*)&Bb[nc0 + l15][kk * 32 + lhi * 8];
            bf16x8 b1 = *(const bf16x8*)&Bb[nc0 + 16 + l15][kk * 32 + lhi * 8];
            acc[0][0] = __builtin_amdgcn_mfma_f32_16x16x32_bf16(a0, b0, acc[0][0], 0, 0, 0);
            acc[0][1] = __builtin_amdgcn_mfma_f32_16x16x32_bf16(a0, b1, acc[0][1], 0, 0, 0);
            acc[1][0] = __builtin_amdgcn_mfma_f32_16x16x32_bf16(a1, b0, acc[1][0], 0, 0, 0);
            acc[1][1] = __builtin_amdgcn_mfma_f32_16x16x32_bf16(a1, b1, acc[1][1], 0, 0, 0);
        }
    }

#pragma unroll
    for (int m = 0; m < 2; ++m)
#pragma unroll
        for (int n = 0; n < 2; ++n)
#pragma unroll
            for (int r = 0; r < 4; ++r) {
                const int grow = i0 + mr0 + 16 * m + 4 * lhi + r;
                const int gcol = j0 + nc0 + 16 * n + l15;
                const int b = grow >> 10, s = grow & 1023;
                const int h = gcol >> 6, d = gcol & 63;
                const float v = acc[m][n][r];
                if (mode == 3) {
                    const size_t idx = (((size_t)(b * H_ + h)) * DH_ + d) * S_ + s;
                    vT[idx] = f2bf(v + bv[gcol]);
                } else {
                    const size_t idx = (((size_t)b * H_ + h) * S_ + s) * DH_ + d;
                    if (mode == 0) {
                        const float base = v + bq[gcol];
                        qu[idx] = f2bf(base + ub[gcol]);
                        qv[idx] = f2bf(base + vb[gcol]);
                    } else if (mode == 1) {
                        kbf[idx] = f2bf(v + bk[gcol]);
                    } else {
                        pbf[idx] = f2bf(v);
                    }
                }
            }
}

// ===========================================================================
// bf16 GEMM with fp32 output: C[4096,512] = A(bf16) @ BT^T (+bias)
// ===========================================================================
__global__ __launch_bounds__(256) void gemm_bf16_k(
    const unsigned short* __restrict__ A,   // [4096,512] bf16
    const unsigned short* __restrict__ BT,  // [512,512] bf16
    const float* __restrict__ bias,
    float* __restrict__ C)                  // [4096,512] fp32
{
    __shared__ unsigned short Ab[64][72];
    __shared__ unsigned short Bb[64][72];
    const int tid = threadIdx.x;
    const int i0 = blockIdx.x * 64, j0 = blockIdx.y * 64;
    const int w = tid >> 6, lane = tid & 63, l15 = lane & 15, lhi = lane >> 4;
    const int mr0 = (w >> 1) * 32, nc0 = (w & 1) * 32;
    f32x4 acc[2][2] = {};

    for (int k0 = 0; k0 < 512; k0 += 64) {
        __syncthreads();
#pragma unroll
        for (int it = 0; it < 2; ++it) {
            const int s = tid + it * 256;
            const int row = s >> 3, g = (s & 7) * 8;
            *(bf16x8*)&Ab[row][g] = *(const bf16x8*)&A[(size_t)(i0 + row) * 512 + k0 + g];
            *(bf16x8*)&Bb[row][g] = *(const bf16x8*)&BT[(size_t)(j0 + row) * 512 + k0 + g];
        }
        __syncthreads();
#pragma unroll
        for (int kk = 0; kk < 2; ++kk) {
            bf16x8 a0 = *(const bf16x8*)&Ab[mr0 + l15][kk * 32 + lhi * 8];
            bf16x8 a1 = *(const bf16x8*)&Ab[mr0 + 16 + l15][kk * 32 + lhi * 8];
            bf16x8 b0 = *(const bf16x8*)&Bb[nc0 + l15][kk * 32 + lhi * 8];
            bf16x8 b1 = *(const bf16x8*)&Bb[nc0 + 16 + l15][kk * 32 + lhi * 8];
            acc[0][0] = __builtin_amdgcn_mfma_f32_16x16x32_bf16(a0, b0, acc[0][0], 0, 0, 0);
            acc[0][1] = __builtin_amdgcn_mfma_f32_16x16x32_bf16(a0, b1, acc[0][1], 0, 0, 0);
            acc[1][0] = __builtin_amdgcn_mfma_f32_16x16x32_bf16(a1, b0, acc[1][0], 0, 0, 0);
            acc[1][1] = __builtin_amdgcn_mfma_f32_16x16x32_bf16(a1, b1, acc[1][1], 0, 0, 0);
        }
    }

#pragma unroll
    for (int m = 0; m < 2; ++m)
#pragma unroll
        for (int n = 0; n < 2; ++n)
#pragma unroll
            for (int r = 0; r < 4; ++r) {
                const int grow = i0 + mr0 + 16 * m + 4 * lhi + r;
                const int gcol = j0 + nc0 + 16 * n + l15;
                C[(size_t)grow * 512 + gcol] = acc[m][n][r] + bias[gcol];
            }
}

// ===========================================================================
// Fused score + softmax + PV kernel, QBLK=16 rows/block, 2 blocks/CU.
// shifted[i,j] = R[i, 1023-i+j] (j<=i) ; 0 (j==i+1) ; R[i+1, j-i-2] (j>=i+2)
// ===========================================================================
#define RS 1032   // padded LDS row stride for R / P (shorts)
#define QBLK 16

__global__ __launch_bounds__(512, 4) void score_fused_k(
    const unsigned short* __restrict__ qu_g,  // [B,H,S,DH]
    const unsigned short* __restrict__ qv_g,
    const unsigned short* __restrict__ kb_g,
    const unsigned short* __restrict__ pb_g,
    const unsigned short* __restrict__ vT_g,  // [B,H,DH,S]
    float* __restrict__ attn,                 // [B,H,S,S]
    unsigned short* __restrict__ ctx_g)       // [B,S,D] bf16
{
    __shared__ unsigned short Qu[16][72];
    __shared__ unsigned short Aq[32][72];
    __shared__ unsigned short Kb[128][72];    // reused as f32 PV-partial buffer
    __shared__ unsigned short Pb[128][72];
    __shared__ unsigned short Rfl[17 * RS];   // reused as P (16 rows) for PV
    __shared__ float red[16][9];

    const int tid = threadIdx.x;
    const int i0 = blockIdx.x * QBLK;
    const int bh = blockIdx.y;
    const int w = tid >> 6, lane = tid & 63, l15 = lane & 15, lhi = lane >> 4;

    const unsigned short* qu_b = qu_g + (size_t)bh * S_ * DH_;
    const unsigned short* qv_b = qv_g + (size_t)bh * S_ * DH_;
    const unsigned short* kb_b = kb_g + (size_t)bh * S_ * DH_;
    const unsigned short* pb_b = pb_g + (size_t)bh * S_ * DH_;

    // ---- stage A-operands (one-time) ----
    if (tid < 128) {                       // Qu: 16 rows x 8 slots of 16B
        const int r = tid >> 3, seg = (tid & 7) * 8;
        *(bf16x8*)&Qu[r][seg] = *(const bf16x8*)&qu_b[(size_t)(i0 + r) * DH_ + seg];
    }
    if (tid < 256) {                       // Aq: 32 rows (clamped)
        const int r = tid >> 3, seg = (tid & 7) * 8;
        const int src = min(i0 + r, S_ - 1);
        *(bf16x8*)&Aq[r][seg] = *(const bf16x8*)&qv_b[(size_t)src * DH_ + seg];
    }

    // ---- main loop: 8 chunks of 128 cols, reg-staged prefetch ----
    bf16x8 kreg[2], preg[2];
#pragma unroll
    for (int it = 0; it < 2; ++it) {       // prologue: load jc=0
        const int s = tid + it * 512;
        const int row = s >> 3, seg = (s & 7) * 8;
        kreg[it] = *(const bf16x8*)&kb_b[(size_t)row * DH_ + seg];
        preg[it] = *(const bf16x8*)&pb_b[(size_t)row * DH_ + seg];
    }

    f32x4 acc[8] = {};
    for (int jc = 0; jc < 8; ++jc) {
        __syncthreads();                   // prior MFMA readers done
#pragma unroll
        for (int it = 0; it < 2; ++it) {
            const int s = tid + it * 512;
            const int row = s >> 3, seg = (s & 7) * 8;
            *(bf16x8*)&Kb[row][seg] = kreg[it];
            *(bf16x8*)&Pb[row][seg] = preg[it];
        }
        if (jc < 7) {
#pragma unroll
            for (int it = 0; it < 2; ++it) {   // prefetch next chunk into regs
                const int s = tid + it * 512;
                const int row = (jc + 1) * 128 + (s >> 3), seg = (s & 7) * 8;
                kreg[it] = *(const bf16x8*)&kb_b[(size_t)row * DH_ + seg];
                preg[it] = *(const bf16x8*)&pb_b[(size_t)row * DH_ + seg];
            }
        }
        __syncthreads();                   // tiles ready

        f32x4 racc[2] = {};
#pragma unroll
        for (int kk = 0; kk < 2; ++kk) {
            bf16x8 pfr = *(const bf16x8*)&Pb[16 * w + l15][kk * 32 + lhi * 8];
            bf16x8 kfr = *(const bf16x8*)&Kb[16 * w + l15][kk * 32 + lhi * 8];
            bf16x8 aq0 = *(const bf16x8*)&Aq[l15][kk * 32 + lhi * 8];
            bf16x8 aq1 = *(const bf16x8*)&Aq[16 + l15][kk * 32 + lhi * 8];
            bf16x8 qf  = *(const bf16x8*)&Qu[l15][kk * 32 + lhi * 8];
            racc[0] = __builtin_amdgcn_mfma_f32_16x16x32_bf16(aq0, pfr, racc[0], 0, 0, 0);
            racc[1] = __builtin_amdgcn_mfma_f32_16x16x32_bf16(aq1, pfr, racc[1], 0, 0, 0);
            acc[jc] = __builtin_amdgcn_mfma_f32_16x16x32_bf16(qf,  kfr, acc[jc], 0, 0, 0);
        }
#pragma unroll
        for (int m = 0; m < 2; ++m)
#pragma unroll
            for (int r = 0; r < 4; ++r) {
                const int row = 16 * m + 4 * lhi + r;
                if (row < 17)
                    Rfl[row * RS + jc * 128 + 16 * w + l15] = f2bf(racc[m][r]);
            }
    }
    __syncthreads();                       // Rfl complete

    // ---- epilogue: rel-shift gather + scale + softmax ----
    const int il = 4 * lhi;                // + r
    float rmax[4], rsum[4];
#pragma unroll
    for (int r = 0; r < 4; ++r) rmax[r] = -3.0e38f;

#pragma unroll
    for (int jc = 0; jc < 8; ++jc)
#pragma unroll
        for (int r = 0; r < 4; ++r) {
            const int row = il + r;
            const int i = i0 + row;
            const int j = jc * 128 + 16 * w + l15;
            float pos = 0.f;
            if (j <= i)          pos = bf2f(Rfl[row * RS + 1023 - i + j]);
            else if (j >= i + 2) pos = bf2f(Rfl[(row + 1) * RS + (j - i - 2)]);
            const float s = (acc[jc][r] + pos) * SCALE;
            acc[jc][r] = s;
            rmax[r] = fmaxf(rmax[r], s);
        }

#pragma unroll
    for (int r = 0; r < 4; ++r)
#pragma unroll
        for (int off = 1; off < 16; off <<= 1)
            rmax[r] = fmaxf(rmax[r], __shfl_xor(rmax[r], off));
    if (l15 == 0)
#pragma unroll
        for (int r = 0; r < 4; ++r) red[il + r][w] = rmax[r];
    __syncthreads();
#pragma unroll
    for (int r = 0; r < 4; ++r) {
        float mx = red[il + r][0];
#pragma unroll
        for (int ww = 1; ww < 8; ++ww) mx = fmaxf(mx, red[il + r][ww]);
        rmax[r] = mx;
        rsum[r] = 0.f;
    }
    __syncthreads();                       // red reads done before reuse

#pragma unroll
    for (int jc = 0; jc < 8; ++jc)
#pragma unroll
        for (int r = 0; r < 4; ++r) {
            const float e = __expf(acc[jc][r] - rmax[r]);
            acc[jc][r] = e;
            rsum[r] += e;
        }
#pragma unroll
    for (int r = 0; r < 4; ++r)
#pragma unroll
        for (int off = 1; off < 16; off <<= 1)
            rsum[r] += __shfl_xor(rsum[r], off);
    if (l15 == 0)
#pragma unroll
        for (int r = 0; r < 4; ++r) red[il + r][w] = rsum[r];
    __syncthreads();

    // ---- normalize: write attn (fp32, global) + P (bf16, LDS in Rfl) ----
    float* attn_b = attn + (size_t)bh * S_ * S_;
#pragma unroll
    for (int r = 0; r < 4; ++r) {
        float sum = red[il + r][0];
#pragma unroll
        for (int ww = 1; ww < 8; ++ww) sum += red[il + r][ww];
        const float inv = 1.f / sum;
#pragma unroll
        for (int jc = 0; jc < 8; ++jc) {
            const int j = jc * 128 + 16 * w + l15;
            const float pn = acc[jc][r] * inv;
            attn_b[(size_t)(i0 + il + r) * S_ + j] = pn;
            Rfl[(il + r) * RS + j] = f2bf(pn);
        }
    }
    __syncthreads();                       // P complete in LDS

    // ---- fused PV: ctx[i0..i0+16, h*64 + 0..64) = P @ V ----
    const int b4 = bh >> 3, h4 = bh & 7;
    const int nblk = w & 3;                // d-block (16 cols)
    const int kh = w >> 2;                 // K-half (512 each)
    const unsigned short* vrow = vT_g + (size_t)bh * DH_ * S_
                               + (size_t)(16 * nblk + l15) * S_;
    f32x4 cacc = {};
#pragma unroll
    for (int ki = 0; ki < 16; ++ki) {
        const int t0 = kh * 512 + ki * 32 + lhi * 8;
        bf16x8 a  = *(const bf16x8*)&Rfl[l15 * RS + t0];
        bf16x8 bb = *(const bf16x8*)&vrow[t0];
        cacc = __builtin_amdgcn_mfma_f32_16x16x32_bf16(a, bb, cacc, 0, 0, 0);
    }
    float* fred = (float*)&Kb[0][0];       // 4*16*16 f32 partials (Kb dead)
    if (kh == 0) {
#pragma unroll
        for (int r = 0; r < 4; ++r)
            fred[(nblk * 16 + 4 * lhi + r) * 16 + l15] = cacc[r];
    }
    __syncthreads();
    if (kh == 1) {
#pragma unroll
        for (int r = 0; r < 4; ++r) {
            const float vs = cacc[r] + fred[(nblk * 16 + 4 * lhi + r) * 16 + l15];
            const int srow = i0 + 4 * lhi + r;
            ctx_g[((size_t)(b4 * S_ + srow)) * D_ + h4 * DH_ + 16 * nblk + l15] = f2bf(vs);
        }
    }
}

// ===========================================================================
extern "C" void kernel_launch(void* const* d_in, const int* in_sizes, int n_in,
                              void* d_out, int out_size, void* d_ws, size_t ws_size,
                              hipStream_t stream)
{
    const float* query = (const float*)d_in[0];
    const float* key_  = (const float*)d_in[1];
    const float* value = (const float*)d_in[2];
    const float* pose  = (const float*)d_in[3];
    const float* Wq = (const float*)d_in[4];
    const float* bq = (const float*)d_in[5];
    const float* Wk = (const float*)d_in[6];
    const float* bk = (const float*)d_in[7];
    const float* Wv = (const float*)d_in[8];
    const float* bv = (const float*)d_in[9];
    const float* Wp = (const float*)d_in[10];
    const float* Wo = (const float*)d_in[11];
    const float* bo = (const float*)d_in[12];
    const float* u_bias = (const float*)d_in[13];
    const float* v_bias = (const float*)d_in[14];

    const size_t NTOK = (size_t)B_ * S_ * D_;   // 2,097,152
    float* out  = (float*)d_out;                // [B,S,D]
    float* attn = (float*)d_out + NTOK;         // [B,H,S,S]

    unsigned short* qu  = (unsigned short*)d_ws;
    unsigned short* qv  = qu + NTOK;
    unsigned short* kbf = qv + NTOK;
    unsigned short* pbf = kbf + NTOK;
    unsigned short* WqT = pbf + NTOK;
    unsigned short* WkT = WqT + 262144;
    unsigned short* WpT = WkT + 262144;
    unsigned short* WvT = WpT + 262144;
    unsigned short* WoT = WvT + 262144;
    unsigned short* vT  = WoT + 262144;         // [B,H,DH,S] bf16
    unsigned short* ctx = vT + NTOK;            // [B,S,D] bf16

    const dim3 blk256(256);
    const dim3 gproj(64, 8);

    convert_wt_k<<<dim3(1024, 5), blk256, 0, stream>>>(Wq, Wk, Wp, Wv, Wo,
                                                       WqT, WkT, WpT, WvT, WoT);

    proj_all_k<<<dim3(64, 8, 4), blk256, 0, stream>>>(
        query, key_, pose, value,
        WqT, WkT, WpT, WvT,
        bq, bk, bv, u_bias, v_bias,
        qu, qv, kbf, pbf, vT);

    score_fused_k<<<dim3(S_ / QBLK, B_ * H_), dim3(512), 0, stream>>>(
        qu, qv, kbf, pbf, vT, attn, ctx);

    gemm_bf16_k<<<gproj, blk256, 0, stream>>>(ctx, WoT, bo, out);
}